// Round 1
// baseline (1698.933 us; speedup 1.0000x reference)
//
#include <hip/hip_runtime.h>
#include <cmath>

#define NN 50000
#define NE 1600000
#define NG 64

static __device__ __forceinline__ float softplusf(float x) {
    return fmaxf(x, 0.0f) + log1pf(expf(-fabsf(x)));
}

__global__ void k_deg_hist(const int* __restrict__ row, const float* __restrict__ w,
                           float* __restrict__ deg, int* __restrict__ cnt) {
    int e = blockIdx.x * blockDim.x + threadIdx.x;
    if (e < NE) {
        int r = row[e];
        atomicAdd(&deg[r], w[e]);
        atomicAdd(&cnt[r], 1);
    }
}

__global__ void k_dinv(float* __restrict__ deg) {
    int i = blockIdx.x * blockDim.x + threadIdx.x;
    if (i < NN) {
        float d = deg[i];
        deg[i] = (d > 0.0f) ? rsqrtf(d) : 0.0f;
    }
}

__global__ void k_scan1(const int* __restrict__ cnt, int* __restrict__ rowptr,
                        int* __restrict__ bsum) {
    __shared__ int sh[256];
    int tid = threadIdx.x;
    int i = blockIdx.x * 256 + tid;
    int v = (i < NN) ? cnt[i] : 0;
    sh[tid] = v;
    __syncthreads();
    for (int off = 1; off < 256; off <<= 1) {
        int t = (tid >= off) ? sh[tid - off] : 0;
        __syncthreads();
        sh[tid] += t;
        __syncthreads();
    }
    if (i < NN) rowptr[i] = sh[tid] - v;
    if (tid == 255) bsum[blockIdx.x] = sh[255];
}

__global__ void k_scan2(int* __restrict__ bsum, int nb) {
    __shared__ int sh[256];
    int tid = threadIdx.x;
    int v = (tid < nb) ? bsum[tid] : 0;
    sh[tid] = v;
    __syncthreads();
    for (int off = 1; off < 256; off <<= 1) {
        int t = (tid >= off) ? sh[tid - off] : 0;
        __syncthreads();
        sh[tid] += t;
        __syncthreads();
    }
    bsum[tid] = sh[tid] - v;
}

__global__ void k_scan3(int* __restrict__ rowptr, const int* __restrict__ bsum) {
    int i = blockIdx.x * 256 + threadIdx.x;
    if (i < NN) rowptr[i] += bsum[blockIdx.x];
    if (i == 0) rowptr[NN] = NE;
}

__global__ void k_scatter(const int* __restrict__ row, const int* __restrict__ col,
                          const float* __restrict__ w, const int* __restrict__ rowptr,
                          int* __restrict__ cursor, const float* __restrict__ dinv,
                          int* __restrict__ ccol, float* __restrict__ cw) {
    int e = blockIdx.x * blockDim.x + threadIdx.x;
    if (e < NE) {
        int r = row[e], c = col[e];
        int p = rowptr[r] + atomicAdd(&cursor[r], 1);
        ccol[p] = c;
        cw[p] = -w[e] * dinv[r] * dinv[c];
    }
}

// Wcat1 (128 x 48) = [W0-W2 | W1 | W2] from W1 input (3,128,16)
__global__ void k_wcat1(const float* __restrict__ W1, float* __restrict__ wc) {
    int i = blockIdx.x * blockDim.x + threadIdx.x;
    if (i < 128 * 48) {
        int k = i / 48, j = i - k * 48;
        float v;
        if (j < 16)      v = W1[k * 16 + j] - W1[2 * 2048 + k * 16 + j];
        else if (j < 32) v = W1[2048 + k * 16 + (j - 16)];
        else             v = W1[2 * 2048 + k * 16 + (j - 32)];
        wc[i] = v;
    }
}

// fp32 GEMM: C[M,Ncol] = A[M,K] @ B[K,Ncol] (+bias, optional softplus)
// 128x128 tile, 8x8 per thread, BK=16. K must be a multiple of 16, Ncol of 4.
__global__ __launch_bounds__(256) void k_gemm(
    const float* __restrict__ A, int lda,
    const float* __restrict__ B, int ldb,
    float* __restrict__ C, int ldc,
    int M, int K, int Ncol,
    const float* __restrict__ bias, int act)
{
    __shared__ float As[16][128];
    __shared__ float Bs[16][128];
    const int tid = threadIdx.x;
    const int tx = tid & 15;
    const int ty = tid >> 4;
    const int bm = blockIdx.y * 128;
    const int bn = blockIdx.x * 128;
    const int arow = tid >> 1;
    const int akq = (tid & 1) * 8;
    const int bkr = tid >> 4;
    const int bcq = (tid & 15) * 8;

    float acc[8][8];
#pragma unroll
    for (int i = 0; i < 8; ++i)
#pragma unroll
        for (int j = 0; j < 8; ++j) acc[i][j] = 0.0f;

    for (int k0 = 0; k0 < K; k0 += 16) {
        float4 a0 = make_float4(0, 0, 0, 0), a1 = make_float4(0, 0, 0, 0);
        int gr = bm + arow;
        if (gr < M) {
            a0 = *(const float4*)(A + gr * lda + k0 + akq);
            a1 = *(const float4*)(A + gr * lda + k0 + akq + 4);
        }
        float4 b0 = make_float4(0, 0, 0, 0), b1 = make_float4(0, 0, 0, 0);
        int cb = bn + bcq;
        const float* Bp = B + (k0 + bkr) * ldb;
        if (cb < Ncol)     b0 = *(const float4*)(Bp + cb);
        if (cb + 4 < Ncol) b1 = *(const float4*)(Bp + cb + 4);
        __syncthreads();
        As[akq + 0][arow] = a0.x; As[akq + 1][arow] = a0.y;
        As[akq + 2][arow] = a0.z; As[akq + 3][arow] = a0.w;
        As[akq + 4][arow] = a1.x; As[akq + 5][arow] = a1.y;
        As[akq + 6][arow] = a1.z; As[akq + 7][arow] = a1.w;
        *(float4*)&Bs[bkr][bcq] = b0;
        *(float4*)&Bs[bkr][bcq + 4] = b1;
        __syncthreads();
#pragma unroll
        for (int kk = 0; kk < 16; ++kk) {
            float a[8], b[8];
            float4 t;
            t = *(const float4*)&As[kk][ty * 4];      a[0] = t.x; a[1] = t.y; a[2] = t.z; a[3] = t.w;
            t = *(const float4*)&As[kk][64 + ty * 4]; a[4] = t.x; a[5] = t.y; a[6] = t.z; a[7] = t.w;
            t = *(const float4*)&Bs[kk][tx * 4];      b[0] = t.x; b[1] = t.y; b[2] = t.z; b[3] = t.w;
            t = *(const float4*)&Bs[kk][64 + tx * 4]; b[4] = t.x; b[5] = t.y; b[6] = t.z; b[7] = t.w;
#pragma unroll
            for (int i = 0; i < 8; ++i)
#pragma unroll
                for (int j = 0; j < 8; ++j)
                    acc[i][j] = fmaf(a[i], b[j], acc[i][j]);
        }
    }
#pragma unroll
    for (int i = 0; i < 8; ++i) {
        int r = bm + ((i < 4) ? (ty * 4 + i) : (64 + ty * 4 + i - 4));
        if (r >= M) continue;
#pragma unroll
        for (int j = 0; j < 8; ++j) {
            int cl = bn + ((j < 4) ? (tx * 4 + j) : (64 + tx * 4 + j - 4));
            if (cl >= Ncol) continue;
            float v = acc[i][j];
            if (bias) v += bias[cl];
            if (act) v = softplusf(v);
            C[r * ldc + cl] = v;
        }
    }
}

// CSR propagation: out[i, :] = alpha * sum_e norm_e * z[col_e, :]  (+ c1*add1 + add2 + bias, softplus)
// T = 1<<ltw lanes per node, each lane owns 4 contiguous features (float4).
__global__ __launch_bounds__(256) void k_prop(
    const int* __restrict__ rowptr, const int* __restrict__ ccol,
    const float* __restrict__ cw,
    const float* __restrict__ z, int zld, int zoff,
    float* __restrict__ out, int outld, int ooff,
    int ltw, float alpha,
    const float* __restrict__ add1, int a1ld, int a1off, float c1,
    const float* __restrict__ add2, int a2ld, int a2off,
    const float* __restrict__ bias, int act)
{
    const int T = 1 << ltw;
    const int lane = threadIdx.x & (T - 1);
    const int node = blockIdx.x * (256 >> ltw) + (threadIdx.x >> ltw);
    if (node >= NN) return;
    const int f4 = lane * 4;
    const int s = rowptr[node];
    const int e = rowptr[node + 1];
    float ax = 0, ay = 0, az = 0, aw = 0;
    const float* zp = z + zoff + f4;
    for (int p = s; p < e; ++p) {
        int c = ccol[p];
        float wv = cw[p];
        const float4 zv = *(const float4*)(zp + c * zld);
        ax = fmaf(wv, zv.x, ax);
        ay = fmaf(wv, zv.y, ay);
        az = fmaf(wv, zv.z, az);
        aw = fmaf(wv, zv.w, aw);
    }
    ax *= alpha; ay *= alpha; az *= alpha; aw *= alpha;
    if (add1) {
        const float4 t = *(const float4*)(add1 + node * a1ld + a1off + f4);
        ax = fmaf(c1, t.x, ax); ay = fmaf(c1, t.y, ay);
        az = fmaf(c1, t.z, az); aw = fmaf(c1, t.w, aw);
    }
    if (add2) {
        const float4 t = *(const float4*)(add2 + node * a2ld + a2off + f4);
        ax += t.x; ay += t.y; az += t.z; aw += t.w;
    }
    if (bias) {
        const float4 t = *(const float4*)(bias + f4);
        ax += t.x; ay += t.y; az += t.z; aw += t.w;
    }
    if (act) { ax = softplusf(ax); ay = softplusf(ay); az = softplusf(az); aw = softplusf(aw); }
    float4 o; o.x = ax; o.y = ay; o.z = az; o.w = aw;
    *(float4*)(out + node * outld + ooff + f4) = o;
}

__global__ __launch_bounds__(256) void k_bnstats(const float* __restrict__ h, int ld, int lc,
                                                 float* __restrict__ stats) {
    const int C = 1 << lc;
    const int tid = threadIdx.x;
    const int c = tid & (C - 1);
    const int rpb = 256 >> lc;
    int r = blockIdx.x * rpb + (tid >> lc);
    const int stride = gridDim.x * rpb;
    float s = 0.0f, q = 0.0f;
    for (; r < NN; r += stride) {
        float v = h[r * ld + c];
        s += v;
        q = fmaf(v, v, q);
    }
    __shared__ float shs[256], shq[256];
    shs[tid] = s; shq[tid] = q;
    __syncthreads();
    for (int o = 128; o >= C; o >>= 1) {
        if (tid < o) { shs[tid] += shs[tid + o]; shq[tid] += shq[tid + o]; }
        __syncthreads();
    }
    if (tid < C) {
        atomicAdd(&stats[c], shs[tid]);
        atomicAdd(&stats[128 + c], shq[tid]);
    }
}

__global__ void k_bnapply(float* __restrict__ h, int ld, int lc,
                          const float* __restrict__ stats,
                          const float* __restrict__ g, const float* __restrict__ be) {
    int idx = blockIdx.x * 256 + threadIdx.x;
    if (idx >= (NN << lc)) return;
    int c = idx & ((1 << lc) - 1);
    int r = idx >> lc;
    const float invN = 1.0f / (float)NN;
    float m = stats[c] * invN;
    float var = fmaf(stats[128 + c], invN, -m * m);
    var = fmaxf(var, 0.0f);
    float inv = rsqrtf(var + 1e-5f);
    float v = h[r * ld + c];
    h[r * ld + c] = fmaf(g[c] * inv, v - m, be[c]);
}

static __device__ __forceinline__ int lower_bound_dev(const int* __restrict__ b, int val) {
    int lo = 0, hi = NN;
    while (lo < hi) {
        int mid = (lo + hi) >> 1;
        if (b[mid] < val) lo = mid + 1; else hi = mid;
    }
    return lo;
}

__global__ __launch_bounds__(256) void k_pool(const float* __restrict__ h,
                                              const int* __restrict__ batch,
                                              float* __restrict__ pooled) {
    int g = blockIdx.x;
    int start = lower_bound_dev(batch, g);
    int end = lower_bound_dev(batch, g + 1);
    int c = threadIdx.x;
    float mx = -INFINITY, sum = 0.0f;
    for (int r = start; r < end; ++r) {
        float v = h[(size_t)r * 256 + c];
        mx = fmaxf(mx, v);
        sum += v;
    }
    float cntf = (float)(end - start);
    pooled[g * 512 + c] = (end > start) ? mx : 0.0f;
    pooled[g * 512 + 256 + c] = sum / fmaxf(cntf, 1.0f);
}

__global__ __launch_bounds__(64) void k_dense(const float* __restrict__ pooled,
                                              const float* __restrict__ Wd,
                                              const float* __restrict__ bd,
                                              float* __restrict__ out) {
    int g = blockIdx.x;
    int t = threadIdx.x;
    float p0 = 0, p1 = 0, p2 = 0, p3 = 0;
    for (int k = t; k < 512; k += 64) {
        float pv = pooled[g * 512 + k];
        p0 = fmaf(pv, Wd[k * 4 + 0], p0);
        p1 = fmaf(pv, Wd[k * 4 + 1], p1);
        p2 = fmaf(pv, Wd[k * 4 + 2], p2);
        p3 = fmaf(pv, Wd[k * 4 + 3], p3);
    }
#pragma unroll
    for (int o = 32; o > 0; o >>= 1) {
        p0 += __shfl_down(p0, o);
        p1 += __shfl_down(p1, o);
        p2 += __shfl_down(p2, o);
        p3 += __shfl_down(p3, o);
    }
    if (t == 0) {
        float l0 = p0 + bd[0], l1 = p1 + bd[1], l2 = p2 + bd[2], l3 = p3 + bd[3];
        float m = fmaxf(fmaxf(l0, l1), fmaxf(l2, l3));
        float ls = m + logf(expf(l0 - m) + expf(l1 - m) + expf(l2 - m) + expf(l3 - m));
        out[g * 4 + 0] = l0 - ls;
        out[g * 4 + 1] = l1 - ls;
        out[g * 4 + 2] = l2 - ls;
        out[g * 4 + 3] = l3 - ls;
    }
}

extern "C" void kernel_launch(void* const* d_in, const int* in_sizes, int n_in,
                              void* d_out, int out_size, void* d_ws, size_t ws_size,
                              hipStream_t stream)
{
    const float* x    = (const float*)d_in[0];
    const float* ew   = (const float*)d_in[1];
    const int*   row  = (const int*)d_in[2];
    const int*   colp = row + NE;
    const int*   batch = (const int*)d_in[3];
    const float* W1 = (const float*)d_in[4];
    const float* b1 = (const float*)d_in[5];
    const float* g1 = (const float*)d_in[6];
    const float* be1 = (const float*)d_in[7];
    const float* W2 = (const float*)d_in[8];
    const float* b2 = (const float*)d_in[9];
    const float* g2 = (const float*)d_in[10];
    const float* be2 = (const float*)d_in[11];
    const float* W3 = (const float*)d_in[12];
    const float* b3 = (const float*)d_in[13];
    const float* g3 = (const float*)d_in[14];
    const float* be3 = (const float*)d_in[15];
    const float* W4 = (const float*)d_in[16];
    const float* b4 = (const float*)d_in[17];
    const float* g4 = (const float*)d_in[18];
    const float* be4 = (const float*)d_in[19];
    const float* W5 = (const float*)d_in[20];
    const float* b5 = (const float*)d_in[21];
    const float* Wd = (const float*)d_in[22];
    const float* bd = (const float*)d_in[23];
    float* outp = (float*)d_out;
    (void)in_sizes; (void)n_in; (void)out_size; (void)ws_size;

    char* wsb = (char*)d_ws;
    size_t off = 0;
    auto take = [&](size_t bytes) -> void* {
        void* p = wsb + off;
        off = (off + bytes + 255) & ~(size_t)255;
        return p;
    };
    int*   rowptr = (int*)take((NN + 1) * sizeof(int));
    int*   cnt    = (int*)take((size_t)NN * sizeof(int));
    int*   cursor = (int*)take((size_t)NN * sizeof(int));
    float* deg    = (float*)take((size_t)NN * sizeof(float));
    int*   bsum   = (int*)take(256 * sizeof(int));
    int*   ccol   = (int*)take((size_t)NE * sizeof(int));
    float* cw     = (float*)take((size_t)NE * sizeof(float));
    float* stats  = (float*)take(256 * sizeof(float));
    float* wcat   = (float*)take(6144 * sizeof(float));
    float* pooled = (float*)take((size_t)64 * 512 * sizeof(float));
    float* bufA   = (float*)take((size_t)NN * 384 * sizeof(float));
    float* bufB   = (float*)take((size_t)NN * 256 * sizeof(float));

    float* P   = bufA;                        // (NN,48) layer-1 pre-transformed
    float* Hc3 = bufA;                        // (NN,96)
    float* Hc5 = bufA;                        // (NN,384)
    float* u   = bufB;                        // (NN,16)
    float* vv  = bufB + (size_t)NN * 16;      // (NN,16)
    float* Hc2 = bufB + (size_t)NN * 32;      // (NN,48)
    float* Hc4 = bufB;                        // (NN,192)
    float* h5  = bufB;                        // (NN,256)

    hipMemsetAsync(deg, 0, NN * sizeof(float), stream);
    hipMemsetAsync(cnt, 0, NN * sizeof(int), stream);
    hipMemsetAsync(cursor, 0, NN * sizeof(int), stream);

    k_deg_hist<<<6250, 256, 0, stream>>>(row, ew, deg, cnt);
    k_dinv<<<196, 256, 0, stream>>>(deg);
    k_scan1<<<196, 256, 0, stream>>>(cnt, rowptr, bsum);
    k_scan2<<<1, 256, 0, stream>>>(bsum, 196);
    k_scan3<<<196, 256, 0, stream>>>(rowptr, bsum);
    k_scatter<<<6250, 256, 0, stream>>>(row, colp, ew, rowptr, cursor, deg, ccol, cw);
    k_wcat1<<<24, 256, 0, stream>>>(W1, wcat);

    // ---- Layer 1 (128 -> 16), transformed: out = P0 + prop(P1) + 2*prop(prop(P2)) + b
    k_gemm<<<dim3(1, 391), 256, 0, stream>>>(x, 128, wcat, 48, P, 48, NN, 128, 48, nullptr, 0);
    k_prop<<<782, 256, 0, stream>>>(rowptr, ccol, cw, P, 48, 16, u, 16, 0, 2, 1.0f,
                                    nullptr, 0, 0, 0.0f, nullptr, 0, 0, nullptr, 0);
    k_prop<<<782, 256, 0, stream>>>(rowptr, ccol, cw, P, 48, 32, vv, 16, 0, 2, 1.0f,
                                    nullptr, 0, 0, 0.0f, nullptr, 0, 0, nullptr, 0);
    k_prop<<<782, 256, 0, stream>>>(rowptr, ccol, cw, vv, 16, 0, Hc2, 48, 0, 2, 2.0f,
                                    P, 48, 0, 1.0f, u, 16, 0, b1, 1);
    hipMemsetAsync(stats, 0, 1024, stream);
    k_bnstats<<<256, 256, 0, stream>>>(Hc2, 48, 4, stats);
    k_bnapply<<<(NN * 16 + 255) / 256, 256, 0, stream>>>(Hc2, 48, 4, stats, g1, be1);

    // ---- Layer 2 (16 -> 32)
    k_prop<<<782, 256, 0, stream>>>(rowptr, ccol, cw, Hc2, 48, 0, Hc2, 48, 16, 2, 1.0f,
                                    nullptr, 0, 0, 0.0f, nullptr, 0, 0, nullptr, 0);
    k_prop<<<782, 256, 0, stream>>>(rowptr, ccol, cw, Hc2, 48, 16, Hc2, 48, 32, 2, 2.0f,
                                    Hc2, 48, 0, -1.0f, nullptr, 0, 0, nullptr, 0);
    k_gemm<<<dim3(1, 391), 256, 0, stream>>>(Hc2, 48, W2, 32, Hc3, 96, NN, 48, 32, b2, 1);
    hipMemsetAsync(stats, 0, 1024, stream);
    k_bnstats<<<256, 256, 0, stream>>>(Hc3, 96, 5, stats);
    k_bnapply<<<(NN * 32 + 255) / 256, 256, 0, stream>>>(Hc3, 96, 5, stats, g2, be2);

    // ---- Layer 3 (32 -> 64)
    k_prop<<<1563, 256, 0, stream>>>(rowptr, ccol, cw, Hc3, 96, 0, Hc3, 96, 32, 3, 1.0f,
                                     nullptr, 0, 0, 0.0f, nullptr, 0, 0, nullptr, 0);
    k_prop<<<1563, 256, 0, stream>>>(rowptr, ccol, cw, Hc3, 96, 32, Hc3, 96, 64, 3, 2.0f,
                                     Hc3, 96, 0, -1.0f, nullptr, 0, 0, nullptr, 0);
    k_gemm<<<dim3(1, 391), 256, 0, stream>>>(Hc3, 96, W3, 64, Hc4, 192, NN, 96, 64, b3, 1);
    hipMemsetAsync(stats, 0, 1024, stream);
    k_bnstats<<<256, 256, 0, stream>>>(Hc4, 192, 6, stats);
    k_bnapply<<<(NN * 64 + 255) / 256, 256, 0, stream>>>(Hc4, 192, 6, stats, g3, be3);

    // ---- Layer 4 (64 -> 128)
    k_prop<<<3125, 256, 0, stream>>>(rowptr, ccol, cw, Hc4, 192, 0, Hc4, 192, 64, 4, 1.0f,
                                     nullptr, 0, 0, 0.0f, nullptr, 0, 0, nullptr, 0);
    k_prop<<<3125, 256, 0, stream>>>(rowptr, ccol, cw, Hc4, 192, 64, Hc4, 192, 128, 4, 2.0f,
                                     Hc4, 192, 0, -1.0f, nullptr, 0, 0, nullptr, 0);
    k_gemm<<<dim3(1, 391), 256, 0, stream>>>(Hc4, 192, W4, 128, Hc5, 384, NN, 192, 128, b4, 1);
    hipMemsetAsync(stats, 0, 1024, stream);
    k_bnstats<<<256, 256, 0, stream>>>(Hc5, 384, 7, stats);
    k_bnapply<<<(NN * 128 + 255) / 256, 256, 0, stream>>>(Hc5, 384, 7, stats, g4, be4);

    // ---- Layer 5 (128 -> 256), no BN/act
    k_prop<<<6250, 256, 0, stream>>>(rowptr, ccol, cw, Hc5, 384, 0, Hc5, 384, 128, 5, 1.0f,
                                     nullptr, 0, 0, 0.0f, nullptr, 0, 0, nullptr, 0);
    k_prop<<<6250, 256, 0, stream>>>(rowptr, ccol, cw, Hc5, 384, 128, Hc5, 384, 256, 5, 2.0f,
                                     Hc5, 384, 0, -1.0f, nullptr, 0, 0, nullptr, 0);
    k_gemm<<<dim3(2, 391), 256, 0, stream>>>(Hc5, 384, W5, 256, h5, 256, NN, 384, 256, b5, 0);

    // ---- Pool + dense + log_softmax
    k_pool<<<64, 256, 0, stream>>>(h5, batch, pooled);
    k_dense<<<64, 64, 0, stream>>>(pooled, Wd, bd, outp);
}

// Round 2
// 1475.412 us; speedup vs baseline: 1.1515x; 1.1515x over previous
//
#include <hip/hip_runtime.h>
#include <cmath>

#define NN 50000
#define NE 1600000
#define NG 64

static __device__ __forceinline__ float softplusf(float x) {
    return fmaxf(x, 0.0f) + log1pf(expf(-fabsf(x)));
}

__global__ void k_deg_hist(const int* __restrict__ row, const float* __restrict__ w,
                           float* __restrict__ deg, int* __restrict__ cnt) {
    int e = blockIdx.x * blockDim.x + threadIdx.x;
    if (e < NE) {
        int r = row[e];
        atomicAdd(&deg[r], w[e]);
        atomicAdd(&cnt[r], 1);
    }
}

__global__ void k_dinv(float* __restrict__ deg) {
    int i = blockIdx.x * blockDim.x + threadIdx.x;
    if (i < NN) {
        float d = deg[i];
        deg[i] = (d > 0.0f) ? rsqrtf(d) : 0.0f;
    }
}

__global__ void k_scan1(const int* __restrict__ cnt, int* __restrict__ rowptr,
                        int* __restrict__ bsum) {
    __shared__ int sh[256];
    int tid = threadIdx.x;
    int i = blockIdx.x * 256 + tid;
    int v = (i < NN) ? cnt[i] : 0;
    sh[tid] = v;
    __syncthreads();
    for (int off = 1; off < 256; off <<= 1) {
        int t = (tid >= off) ? sh[tid - off] : 0;
        __syncthreads();
        sh[tid] += t;
        __syncthreads();
    }
    if (i < NN) rowptr[i] = sh[tid] - v;
    if (tid == 255) bsum[blockIdx.x] = sh[255];
}

__global__ void k_scan2(int* __restrict__ bsum, int nb) {
    __shared__ int sh[256];
    int tid = threadIdx.x;
    int v = (tid < nb) ? bsum[tid] : 0;
    sh[tid] = v;
    __syncthreads();
    for (int off = 1; off < 256; off <<= 1) {
        int t = (tid >= off) ? sh[tid - off] : 0;
        __syncthreads();
        sh[tid] += t;
        __syncthreads();
    }
    bsum[tid] = sh[tid] - v;
}

__global__ void k_scan3(int* __restrict__ rowptr, const int* __restrict__ bsum) {
    int i = blockIdx.x * 256 + threadIdx.x;
    if (i < NN) rowptr[i] += bsum[blockIdx.x];
    if (i == 0) rowptr[NN] = NE;
}

__global__ void k_scatter(const int* __restrict__ row, const int* __restrict__ col,
                          const float* __restrict__ w, const int* __restrict__ rowptr,
                          int* __restrict__ cursor, const float* __restrict__ dinv,
                          int* __restrict__ ccol, float* __restrict__ cw) {
    int e = blockIdx.x * blockDim.x + threadIdx.x;
    if (e < NE) {
        int r = row[e], c = col[e];
        int p = rowptr[r] + atomicAdd(&cursor[r], 1);
        ccol[p] = c;
        cw[p] = -w[e] * dinv[r] * dinv[c];
    }
}

// Wcat1 (128 x 48) = [W0-W2 | W1 | W2] from W1 input (3,128,16)
__global__ void k_wcat1(const float* __restrict__ W1, float* __restrict__ wc) {
    int i = blockIdx.x * blockDim.x + threadIdx.x;
    if (i < 128 * 48) {
        int k = i / 48, j = i - k * 48;
        float v;
        if (j < 16)      v = W1[k * 16 + j] - W1[2 * 2048 + k * 16 + j];
        else if (j < 32) v = W1[2048 + k * 16 + (j - 16)];
        else             v = W1[2 * 2048 + k * 16 + (j - 32)];
        wc[i] = v;
    }
}

// fp32 GEMM: C[M,Ncol] = A[M,K] @ B[K,Ncol] (+bias, optional softplus)
// 128x128 tile, 8x8 per thread, BK=16. K must be a multiple of 16, Ncol of 4.
__global__ __launch_bounds__(256) void k_gemm(
    const float* __restrict__ A, int lda,
    const float* __restrict__ B, int ldb,
    float* __restrict__ C, int ldc,
    int M, int K, int Ncol,
    const float* __restrict__ bias, int act)
{
    __shared__ float As[16][128];
    __shared__ float Bs[16][128];
    const int tid = threadIdx.x;
    const int tx = tid & 15;
    const int ty = tid >> 4;
    const int bm = blockIdx.y * 128;
    const int bn = blockIdx.x * 128;
    const int arow = tid >> 1;
    const int akq = (tid & 1) * 8;
    const int bkr = tid >> 4;
    const int bcq = (tid & 15) * 8;

    float acc[8][8];
#pragma unroll
    for (int i = 0; i < 8; ++i)
#pragma unroll
        for (int j = 0; j < 8; ++j) acc[i][j] = 0.0f;

    for (int k0 = 0; k0 < K; k0 += 16) {
        float4 a0 = make_float4(0, 0, 0, 0), a1 = make_float4(0, 0, 0, 0);
        int gr = bm + arow;
        if (gr < M) {
            a0 = *(const float4*)(A + gr * lda + k0 + akq);
            a1 = *(const float4*)(A + gr * lda + k0 + akq + 4);
        }
        float4 b0 = make_float4(0, 0, 0, 0), b1 = make_float4(0, 0, 0, 0);
        int cb = bn + bcq;
        const float* Bp = B + (k0 + bkr) * ldb;
        if (cb < Ncol)     b0 = *(const float4*)(Bp + cb);
        if (cb + 4 < Ncol) b1 = *(const float4*)(Bp + cb + 4);
        __syncthreads();
        As[akq + 0][arow] = a0.x; As[akq + 1][arow] = a0.y;
        As[akq + 2][arow] = a0.z; As[akq + 3][arow] = a0.w;
        As[akq + 4][arow] = a1.x; As[akq + 5][arow] = a1.y;
        As[akq + 6][arow] = a1.z; As[akq + 7][arow] = a1.w;
        *(float4*)&Bs[bkr][bcq] = b0;
        *(float4*)&Bs[bkr][bcq + 4] = b1;
        __syncthreads();
#pragma unroll
        for (int kk = 0; kk < 16; ++kk) {
            float a[8], b[8];
            float4 t;
            t = *(const float4*)&As[kk][ty * 4];      a[0] = t.x; a[1] = t.y; a[2] = t.z; a[3] = t.w;
            t = *(const float4*)&As[kk][64 + ty * 4]; a[4] = t.x; a[5] = t.y; a[6] = t.z; a[7] = t.w;
            t = *(const float4*)&Bs[kk][tx * 4];      b[0] = t.x; b[1] = t.y; b[2] = t.z; b[3] = t.w;
            t = *(const float4*)&Bs[kk][64 + tx * 4]; b[4] = t.x; b[5] = t.y; b[6] = t.z; b[7] = t.w;
#pragma unroll
            for (int i = 0; i < 8; ++i)
#pragma unroll
                for (int j = 0; j < 8; ++j)
                    acc[i][j] = fmaf(a[i], b[j], acc[i][j]);
        }
    }
#pragma unroll
    for (int i = 0; i < 8; ++i) {
        int r = bm + ((i < 4) ? (ty * 4 + i) : (64 + ty * 4 + i - 4));
        if (r >= M) continue;
#pragma unroll
        for (int j = 0; j < 8; ++j) {
            int cl = bn + ((j < 4) ? (tx * 4 + j) : (64 + tx * 4 + j - 4));
            if (cl >= Ncol) continue;
            float v = acc[i][j];
            if (bias) v += bias[cl];
            if (act) v = softplusf(v);
            C[r * ldc + cl] = v;
        }
    }
}

// CSR propagation: out[i, :] = alpha * sum_e norm_e * z[col_e, :]  (+ c1*add1 + add2 + bias, softplus)
// T = 1<<ltw lanes per node, each lane owns 4 contiguous features (float4).
__global__ __launch_bounds__(256) void k_prop(
    const int* __restrict__ rowptr, const int* __restrict__ ccol,
    const float* __restrict__ cw,
    const float* __restrict__ z, int zld, int zoff,
    float* __restrict__ out, int outld, int ooff,
    int ltw, float alpha,
    const float* __restrict__ add1, int a1ld, int a1off, float c1,
    const float* __restrict__ add2, int a2ld, int a2off,
    const float* __restrict__ bias, int act)
{
    const int T = 1 << ltw;
    const int lane = threadIdx.x & (T - 1);
    const int node = blockIdx.x * (256 >> ltw) + (threadIdx.x >> ltw);
    if (node >= NN) return;
    const int f4 = lane * 4;
    const int s = rowptr[node];
    const int e = rowptr[node + 1];
    float ax = 0, ay = 0, az = 0, aw = 0;
    const float* zp = z + zoff + f4;
    for (int p = s; p < e; ++p) {
        int c = ccol[p];
        float wv = cw[p];
        const float4 zv = *(const float4*)(zp + c * zld);
        ax = fmaf(wv, zv.x, ax);
        ay = fmaf(wv, zv.y, ay);
        az = fmaf(wv, zv.z, az);
        aw = fmaf(wv, zv.w, aw);
    }
    ax *= alpha; ay *= alpha; az *= alpha; aw *= alpha;
    if (add1) {
        const float4 t = *(const float4*)(add1 + node * a1ld + a1off + f4);
        ax = fmaf(c1, t.x, ax); ay = fmaf(c1, t.y, ay);
        az = fmaf(c1, t.z, az); aw = fmaf(c1, t.w, aw);
    }
    if (add2) {
        const float4 t = *(const float4*)(add2 + node * a2ld + a2off + f4);
        ax += t.x; ay += t.y; az += t.z; aw += t.w;
    }
    if (bias) {
        const float4 t = *(const float4*)(bias + f4);
        ax += t.x; ay += t.y; az += t.z; aw += t.w;
    }
    if (act) { ax = softplusf(ax); ay = softplusf(ay); az = softplusf(az); aw = softplusf(aw); }
    float4 o; o.x = ax; o.y = ay; o.z = az; o.w = aw;
    *(float4*)(out + node * outld + ooff + f4) = o;
}

__global__ __launch_bounds__(256) void k_bnstats(const float* __restrict__ h, int ld, int lc,
                                                 float* __restrict__ stats) {
    const int C = 1 << lc;
    const int tid = threadIdx.x;
    const int c = tid & (C - 1);
    const int rpb = 256 >> lc;
    int r = blockIdx.x * rpb + (tid >> lc);
    const int stride = gridDim.x * rpb;
    float s = 0.0f, q = 0.0f;
    for (; r < NN; r += stride) {
        float v = h[r * ld + c];
        s += v;
        q = fmaf(v, v, q);
    }
    __shared__ float shs[256], shq[256];
    shs[tid] = s; shq[tid] = q;
    __syncthreads();
    for (int o = 128; o >= C; o >>= 1) {
        if (tid < o) { shs[tid] += shs[tid + o]; shq[tid] += shq[tid + o]; }
        __syncthreads();
    }
    if (tid < C) {
        atomicAdd(&stats[c], shs[tid]);
        atomicAdd(&stats[128 + c], shq[tid]);
    }
}

__global__ void k_bnapply(float* __restrict__ h, int ld, int lc,
                          const float* __restrict__ stats,
                          const float* __restrict__ g, const float* __restrict__ be) {
    int idx = blockIdx.x * 256 + threadIdx.x;
    if (idx >= (NN << lc)) return;
    int c = idx & ((1 << lc) - 1);
    int r = idx >> lc;
    const float invN = 1.0f / (float)NN;
    float m = stats[c] * invN;
    float var = fmaf(stats[128 + c], invN, -m * m);
    var = fmaxf(var, 0.0f);
    float inv = rsqrtf(var + 1e-5f);
    float v = h[r * ld + c];
    h[r * ld + c] = fmaf(g[c] * inv, v - m, be[c]);
}

static __device__ __forceinline__ int lower_bound_dev(const int* __restrict__ b, int val) {
    int lo = 0, hi = NN;
    while (lo < hi) {
        int mid = (lo + hi) >> 1;
        if (b[mid] < val) lo = mid + 1; else hi = mid;
    }
    return lo;
}

__global__ void k_gbounds(const int* __restrict__ batch, int* __restrict__ gb) {
    int g = threadIdx.x;
    if (g <= NG) gb[g] = (g == NG) ? NN : lower_bound_dev(batch, g);
}

// Stage 1: grid (chunks=16, graphs=64), 256 threads = channels.
// partial[(g*16+j)][c] = max, partial[...][256+c] = sum over this chunk's rows.
__global__ __launch_bounds__(256) void k_pool1(const float* __restrict__ h,
                                               const int* __restrict__ gb,
                                               float* __restrict__ partial) {
    int g = blockIdx.y;
    int j = blockIdx.x;
    int start = gb[g], end = gb[g + 1];
    int len = end - start;
    int chunk = (len + 15) >> 4;
    int s = start + j * chunk;
    int e = min(s + chunk, end);
    int c = threadIdx.x;
    float mx = -INFINITY, sum = 0.0f;
    for (int r = s; r < e; ++r) {
        float v = h[(size_t)r * 256 + c];
        mx = fmaxf(mx, v);
        sum += v;
    }
    size_t base = ((size_t)(g * 16 + j)) * 512;
    partial[base + c] = mx;
    partial[base + 256 + c] = sum;
}

// Stage 2: 64 blocks × 256 threads; reduce 16 partials, write pooled [G,512].
__global__ __launch_bounds__(256) void k_pool2(const float* __restrict__ partial,
                                               const int* __restrict__ gb,
                                               float* __restrict__ pooled) {
    int g = blockIdx.x;
    int c = threadIdx.x;
    float mx = -INFINITY, sum = 0.0f;
#pragma unroll
    for (int j = 0; j < 16; ++j) {
        size_t base = ((size_t)(g * 16 + j)) * 512;
        mx = fmaxf(mx, partial[base + c]);
        sum += partial[base + 256 + c];
    }
    int len = gb[g + 1] - gb[g];
    pooled[g * 512 + c] = (len > 0) ? mx : 0.0f;
    pooled[g * 512 + 256 + c] = sum / fmaxf((float)len, 1.0f);
}

__global__ __launch_bounds__(64) void k_dense(const float* __restrict__ pooled,
                                              const float* __restrict__ Wd,
                                              const float* __restrict__ bd,
                                              float* __restrict__ out) {
    int g = blockIdx.x;
    int t = threadIdx.x;
    float p0 = 0, p1 = 0, p2 = 0, p3 = 0;
    for (int k = t; k < 512; k += 64) {
        float pv = pooled[g * 512 + k];
        p0 = fmaf(pv, Wd[k * 4 + 0], p0);
        p1 = fmaf(pv, Wd[k * 4 + 1], p1);
        p2 = fmaf(pv, Wd[k * 4 + 2], p2);
        p3 = fmaf(pv, Wd[k * 4 + 3], p3);
    }
#pragma unroll
    for (int o = 32; o > 0; o >>= 1) {
        p0 += __shfl_down(p0, o);
        p1 += __shfl_down(p1, o);
        p2 += __shfl_down(p2, o);
        p3 += __shfl_down(p3, o);
    }
    if (t == 0) {
        float l0 = p0 + bd[0], l1 = p1 + bd[1], l2 = p2 + bd[2], l3 = p3 + bd[3];
        float m = fmaxf(fmaxf(l0, l1), fmaxf(l2, l3));
        float ls = m + logf(expf(l0 - m) + expf(l1 - m) + expf(l2 - m) + expf(l3 - m));
        out[g * 4 + 0] = l0 - ls;
        out[g * 4 + 1] = l1 - ls;
        out[g * 4 + 2] = l2 - ls;
        out[g * 4 + 3] = l3 - ls;
    }
}

extern "C" void kernel_launch(void* const* d_in, const int* in_sizes, int n_in,
                              void* d_out, int out_size, void* d_ws, size_t ws_size,
                              hipStream_t stream)
{
    const float* x    = (const float*)d_in[0];
    const float* ew   = (const float*)d_in[1];
    const int*   row  = (const int*)d_in[2];
    const int*   colp = row + NE;
    const int*   batch = (const int*)d_in[3];
    const float* W1 = (const float*)d_in[4];
    const float* b1 = (const float*)d_in[5];
    const float* g1 = (const float*)d_in[6];
    const float* be1 = (const float*)d_in[7];
    const float* W2 = (const float*)d_in[8];
    const float* b2 = (const float*)d_in[9];
    const float* g2 = (const float*)d_in[10];
    const float* be2 = (const float*)d_in[11];
    const float* W3 = (const float*)d_in[12];
    const float* b3 = (const float*)d_in[13];
    const float* g3 = (const float*)d_in[14];
    const float* be3 = (const float*)d_in[15];
    const float* W4 = (const float*)d_in[16];
    const float* b4 = (const float*)d_in[17];
    const float* g4 = (const float*)d_in[18];
    const float* be4 = (const float*)d_in[19];
    const float* W5 = (const float*)d_in[20];
    const float* b5 = (const float*)d_in[21];
    const float* Wd = (const float*)d_in[22];
    const float* bd = (const float*)d_in[23];
    float* outp = (float*)d_out;
    (void)in_sizes; (void)n_in; (void)out_size; (void)ws_size;

    char* wsb = (char*)d_ws;
    size_t off = 0;
    auto take = [&](size_t bytes) -> void* {
        void* p = wsb + off;
        off = (off + bytes + 255) & ~(size_t)255;
        return p;
    };
    int*   rowptr = (int*)take((NN + 1) * sizeof(int));
    int*   cnt    = (int*)take((size_t)NN * sizeof(int));
    int*   cursor = (int*)take((size_t)NN * sizeof(int));
    float* deg    = (float*)take((size_t)NN * sizeof(float));
    int*   bsum   = (int*)take(256 * sizeof(int));
    int*   gb     = (int*)take((NG + 1) * sizeof(int));
    int*   ccol   = (int*)take((size_t)NE * sizeof(int));
    float* cw     = (float*)take((size_t)NE * sizeof(float));
    float* stats  = (float*)take(256 * sizeof(float));
    float* wcat   = (float*)take(6144 * sizeof(float));
    float* partial= (float*)take((size_t)NG * 16 * 512 * sizeof(float));
    float* pooled = (float*)take((size_t)NG * 512 * sizeof(float));
    float* bufA   = (float*)take((size_t)NN * 384 * sizeof(float));
    float* bufB   = (float*)take((size_t)NN * 256 * sizeof(float));

    float* P   = bufA;                        // (NN,48) layer-1 pre-transformed
    float* Hc3 = bufA;                        // (NN,96)
    float* Hc5 = bufA;                        // (NN,384)
    float* u   = bufB;                        // (NN,16)
    float* vv  = bufB + (size_t)NN * 16;      // (NN,16)
    float* Hc2 = bufB + (size_t)NN * 32;      // (NN,48)
    float* Hc4 = bufB;                        // (NN,192)
    float* h5  = bufB;                        // (NN,256)

    hipMemsetAsync(deg, 0, NN * sizeof(float), stream);
    hipMemsetAsync(cnt, 0, NN * sizeof(int), stream);
    hipMemsetAsync(cursor, 0, NN * sizeof(int), stream);

    k_deg_hist<<<6250, 256, 0, stream>>>(row, ew, deg, cnt);
    k_dinv<<<196, 256, 0, stream>>>(deg);
    k_scan1<<<196, 256, 0, stream>>>(cnt, rowptr, bsum);
    k_scan2<<<1, 256, 0, stream>>>(bsum, 196);
    k_scan3<<<196, 256, 0, stream>>>(rowptr, bsum);
    k_scatter<<<6250, 256, 0, stream>>>(row, colp, ew, rowptr, cursor, deg, ccol, cw);
    k_wcat1<<<24, 256, 0, stream>>>(W1, wcat);
    k_gbounds<<<1, 128, 0, stream>>>(batch, gb);

    // ---- Layer 1 (128 -> 16), transformed: out = P0 + prop(P1) + 2*prop(prop(P2)) + b
    k_gemm<<<dim3(1, 391), 256, 0, stream>>>(x, 128, wcat, 48, P, 48, NN, 128, 48, nullptr, 0);
    k_prop<<<782, 256, 0, stream>>>(rowptr, ccol, cw, P, 48, 16, u, 16, 0, 2, 1.0f,
                                    nullptr, 0, 0, 0.0f, nullptr, 0, 0, nullptr, 0);
    k_prop<<<782, 256, 0, stream>>>(rowptr, ccol, cw, P, 48, 32, vv, 16, 0, 2, 1.0f,
                                    nullptr, 0, 0, 0.0f, nullptr, 0, 0, nullptr, 0);
    k_prop<<<782, 256, 0, stream>>>(rowptr, ccol, cw, vv, 16, 0, Hc2, 48, 0, 2, 2.0f,
                                    P, 48, 0, 1.0f, u, 16, 0, b1, 1);
    hipMemsetAsync(stats, 0, 1024, stream);
    k_bnstats<<<256, 256, 0, stream>>>(Hc2, 48, 4, stats);
    k_bnapply<<<(NN * 16 + 255) / 256, 256, 0, stream>>>(Hc2, 48, 4, stats, g1, be1);

    // ---- Layer 2 (16 -> 32)
    k_prop<<<782, 256, 0, stream>>>(rowptr, ccol, cw, Hc2, 48, 0, Hc2, 48, 16, 2, 1.0f,
                                    nullptr, 0, 0, 0.0f, nullptr, 0, 0, nullptr, 0);
    k_prop<<<782, 256, 0, stream>>>(rowptr, ccol, cw, Hc2, 48, 16, Hc2, 48, 32, 2, 2.0f,
                                    Hc2, 48, 0, -1.0f, nullptr, 0, 0, nullptr, 0);
    k_gemm<<<dim3(1, 391), 256, 0, stream>>>(Hc2, 48, W2, 32, Hc3, 96, NN, 48, 32, b2, 1);
    hipMemsetAsync(stats, 0, 1024, stream);
    k_bnstats<<<256, 256, 0, stream>>>(Hc3, 96, 5, stats);
    k_bnapply<<<(NN * 32 + 255) / 256, 256, 0, stream>>>(Hc3, 96, 5, stats, g2, be2);

    // ---- Layer 3 (32 -> 64)
    k_prop<<<1563, 256, 0, stream>>>(rowptr, ccol, cw, Hc3, 96, 0, Hc3, 96, 32, 3, 1.0f,
                                     nullptr, 0, 0, 0.0f, nullptr, 0, 0, nullptr, 0);
    k_prop<<<1563, 256, 0, stream>>>(rowptr, ccol, cw, Hc3, 96, 32, Hc3, 96, 64, 3, 2.0f,
                                     Hc3, 96, 0, -1.0f, nullptr, 0, 0, nullptr, 0);
    k_gemm<<<dim3(1, 391), 256, 0, stream>>>(Hc3, 96, W3, 64, Hc4, 192, NN, 96, 64, b3, 1);
    hipMemsetAsync(stats, 0, 1024, stream);
    k_bnstats<<<256, 256, 0, stream>>>(Hc4, 192, 6, stats);
    k_bnapply<<<(NN * 64 + 255) / 256, 256, 0, stream>>>(Hc4, 192, 6, stats, g3, be3);

    // ---- Layer 4 (64 -> 128)
    k_prop<<<3125, 256, 0, stream>>>(rowptr, ccol, cw, Hc4, 192, 0, Hc4, 192, 64, 4, 1.0f,
                                     nullptr, 0, 0, 0.0f, nullptr, 0, 0, nullptr, 0);
    k_prop<<<3125, 256, 0, stream>>>(rowptr, ccol, cw, Hc4, 192, 64, Hc4, 192, 128, 4, 2.0f,
                                     Hc4, 192, 0, -1.0f, nullptr, 0, 0, nullptr, 0);
    k_gemm<<<dim3(1, 391), 256, 0, stream>>>(Hc4, 192, W4, 128, Hc5, 384, NN, 192, 128, b4, 1);
    hipMemsetAsync(stats, 0, 1024, stream);
    k_bnstats<<<256, 256, 0, stream>>>(Hc5, 384, 7, stats);
    k_bnapply<<<(NN * 128 + 255) / 256, 256, 0, stream>>>(Hc5, 384, 7, stats, g4, be4);

    // ---- Layer 5 (128 -> 256), no BN/act
    k_prop<<<6250, 256, 0, stream>>>(rowptr, ccol, cw, Hc5, 384, 0, Hc5, 384, 128, 5, 1.0f,
                                     nullptr, 0, 0, 0.0f, nullptr, 0, 0, nullptr, 0);
    k_prop<<<6250, 256, 0, stream>>>(rowptr, ccol, cw, Hc5, 384, 128, Hc5, 384, 256, 5, 2.0f,
                                     Hc5, 384, 0, -1.0f, nullptr, 0, 0, nullptr, 0);
    k_gemm<<<dim3(2, 391), 256, 0, stream>>>(Hc5, 384, W5, 256, h5, 256, NN, 384, 256, b5, 0);

    // ---- Pool + dense + log_softmax
    k_pool1<<<dim3(16, 64), 256, 0, stream>>>(h5, gb, partial);
    k_pool2<<<64, 256, 0, stream>>>(partial, gb, pooled);
    k_dense<<<64, 64, 0, stream>>>(pooled, Wd, bd, outp);
}

// Round 3
// 1243.918 us; speedup vs baseline: 1.3658x; 1.1861x over previous
//
#include <hip/hip_runtime.h>
#include <cmath>

#define NN 50000
#define NE 1600000
#define NG 64

typedef __attribute__((ext_vector_type(8))) short short8_t;
typedef __attribute__((ext_vector_type(4))) float floatx4;

static __device__ __forceinline__ float softplusf(float x) {
    return fmaxf(x, 0.0f) + log1pf(expf(-fabsf(x)));
}

// exact split x = hi + lo (bf16 each, ~2^-16 relative residual)
static __device__ __forceinline__ void split_bf16(float x, unsigned short& hi, unsigned short& lo) {
    unsigned u = __float_as_uint(x);
    unsigned hb = u & 0xFFFF0000u;
    hi = (unsigned short)(hb >> 16);
    float r = x - __uint_as_float(hb);   // exact
    unsigned v = __float_as_uint(r);
    unsigned t = (v >> 16) & 1u;
    lo = (unsigned short)((v + 0x7FFFu + t) >> 16);  // RNE
}

__global__ void k_deg_hist(const int* __restrict__ row, const float* __restrict__ w,
                           float* __restrict__ deg, int* __restrict__ cnt) {
    int e = blockIdx.x * blockDim.x + threadIdx.x;
    if (e < NE) {
        int r = row[e];
        atomicAdd(&deg[r], w[e]);
        atomicAdd(&cnt[r], 1);
    }
}

__global__ void k_dinv(float* __restrict__ deg) {
    int i = blockIdx.x * blockDim.x + threadIdx.x;
    if (i < NN) {
        float d = deg[i];
        deg[i] = (d > 0.0f) ? rsqrtf(d) : 0.0f;
    }
}

__global__ void k_scan1(const int* __restrict__ cnt, int* __restrict__ rowptr,
                        int* __restrict__ bsum) {
    __shared__ int sh[256];
    int tid = threadIdx.x;
    int i = blockIdx.x * 256 + tid;
    int v = (i < NN) ? cnt[i] : 0;
    sh[tid] = v;
    __syncthreads();
    for (int off = 1; off < 256; off <<= 1) {
        int t = (tid >= off) ? sh[tid - off] : 0;
        __syncthreads();
        sh[tid] += t;
        __syncthreads();
    }
    if (i < NN) rowptr[i] = sh[tid] - v;
    if (tid == 255) bsum[blockIdx.x] = sh[255];
}

__global__ void k_scan2(int* __restrict__ bsum, int nb) {
    __shared__ int sh[256];
    int tid = threadIdx.x;
    int v = (tid < nb) ? bsum[tid] : 0;
    sh[tid] = v;
    __syncthreads();
    for (int off = 1; off < 256; off <<= 1) {
        int t = (tid >= off) ? sh[tid - off] : 0;
        __syncthreads();
        sh[tid] += t;
        __syncthreads();
    }
    bsum[tid] = sh[tid] - v;
}

__global__ void k_scan3(int* __restrict__ rowptr, const int* __restrict__ bsum) {
    int i = blockIdx.x * 256 + threadIdx.x;
    if (i < NN) rowptr[i] += bsum[blockIdx.x];
    if (i == 0) rowptr[NN] = NE;
}

__global__ void k_scatter(const int* __restrict__ row, const int* __restrict__ col,
                          const float* __restrict__ w, const int* __restrict__ rowptr,
                          int* __restrict__ cursor, const float* __restrict__ dinv,
                          int* __restrict__ ccol, float* __restrict__ cw) {
    int e = blockIdx.x * blockDim.x + threadIdx.x;
    if (e < NE) {
        int r = row[e], c = col[e];
        int p = rowptr[r] + atomicAdd(&cursor[r], 1);
        ccol[p] = c;
        cw[p] = -w[e] * dinv[r] * dinv[c];
    }
}

// Wcat1 (128 x 48) = [W0-W2 | W1 | W2] from W1 input (3,128,16)
__global__ void k_wcat1(const float* __restrict__ W1, float* __restrict__ wc) {
    int i = blockIdx.x * blockDim.x + threadIdx.x;
    if (i < 128 * 48) {
        int k = i / 48, j = i - k * 48;
        float v;
        if (j < 16)      v = W1[k * 16 + j] - W1[2 * 2048 + k * 16 + j];
        else if (j < 32) v = W1[2048 + k * 16 + (j - 16)];
        else             v = W1[2 * 2048 + k * 16 + (j - 32)];
        wc[i] = v;
    }
}

// Split W (K,N) fp32 into transposed hi/lo bf16: hiT/loT are (N,K)
__global__ void k_wsplit(const float* __restrict__ W, int K, int N,
                         unsigned short* __restrict__ hiT, unsigned short* __restrict__ loT) {
    int idx = blockIdx.x * 256 + threadIdx.x;
    if (idx < K * N) {
        int k = idx / N, n = idx - k * N;
        unsigned short h, l;
        split_bf16(W[idx], h, l);
        hiT[(size_t)n * K + k] = h;
        loT[(size_t)n * K + k] = l;
    }
}

// ---------------- MFMA split-bf16 GEMM ----------------
// C[M,Ncol] = A[M,K](fp32) @ B[K,Ncol]  via 3-term hi/lo bf16 MFMA.
// B pre-split+transposed: BhiT/BloT are (Ncol, K) bf16 bits.
// Tile 128x128, BK=32, 4 waves (2x2), each wave 4x4 of 16x16x32 mfma.
// K must be a multiple of 32.
#define ASTR 40  // padded LDS row stride in ushorts (32 + 8)

__global__ __launch_bounds__(256, 2) void k_gemm_mfma(
    const float* __restrict__ A, int lda,
    const unsigned short* __restrict__ BhiT,
    const unsigned short* __restrict__ BloT,
    float* __restrict__ C, int ldc,
    int M, int K, int Ncol,
    const float* __restrict__ bias, int act)
{
    __shared__ unsigned short Ah[128 * ASTR];
    __shared__ unsigned short Al[128 * ASTR];
    __shared__ unsigned short Bh[128 * ASTR];
    __shared__ unsigned short Bl[128 * ASTR];

    const int tid = threadIdx.x;
    const int lane = tid & 63;
    const int wave = tid >> 6;
    const int wm = wave >> 1, wn = wave & 1;
    const int quad = lane >> 4, l16 = lane & 15;
    const int bm = blockIdx.y * 128, bn = blockIdx.x * 128;

    const int srow = tid >> 1;        // 0..127
    const int skq  = (tid & 1) * 16;  // 0 or 16

    floatx4 acc[4][4];
#pragma unroll
    for (int i = 0; i < 4; ++i)
#pragma unroll
        for (int j = 0; j < 4; ++j) acc[i][j] = (floatx4){0.f, 0.f, 0.f, 0.f};

    for (int k0 = 0; k0 < K; k0 += 32) {
        // ---- global loads
        float4 a0 = make_float4(0, 0, 0, 0), a1 = a0, a2 = a0, a3 = a0;
        const int ga = bm + srow;
        if (ga < M) {
            const float* Ap = A + (size_t)ga * lda + k0 + skq;
            a0 = *(const float4*)(Ap + 0);
            a1 = *(const float4*)(Ap + 4);
            a2 = *(const float4*)(Ap + 8);
            a3 = *(const float4*)(Ap + 12);
        }
        uint4 bh0 = make_uint4(0, 0, 0, 0), bh1 = bh0, bl0 = bh0, bl1 = bh0;
        const int gb = bn + srow;
        if (gb < Ncol) {
            const unsigned short* ph = BhiT + (size_t)gb * K + k0 + skq;
            const unsigned short* pl = BloT + (size_t)gb * K + k0 + skq;
            bh0 = *(const uint4*)(ph);
            bh1 = *(const uint4*)(ph + 8);
            bl0 = *(const uint4*)(pl);
            bl1 = *(const uint4*)(pl + 8);
        }
        __attribute__((aligned(16))) unsigned short ah[16], al[16];
        const float av[16] = {a0.x, a0.y, a0.z, a0.w, a1.x, a1.y, a1.z, a1.w,
                              a2.x, a2.y, a2.z, a2.w, a3.x, a3.y, a3.z, a3.w};
#pragma unroll
        for (int i = 0; i < 16; ++i) split_bf16(av[i], ah[i], al[i]);

        __syncthreads();
        *(uint4*)&Ah[srow * ASTR + skq]     = *(const uint4*)&ah[0];
        *(uint4*)&Ah[srow * ASTR + skq + 8] = *(const uint4*)&ah[8];
        *(uint4*)&Al[srow * ASTR + skq]     = *(const uint4*)&al[0];
        *(uint4*)&Al[srow * ASTR + skq + 8] = *(const uint4*)&al[8];
        *(uint4*)&Bh[srow * ASTR + skq]     = bh0;
        *(uint4*)&Bh[srow * ASTR + skq + 8] = bh1;
        *(uint4*)&Bl[srow * ASTR + skq]     = bl0;
        *(uint4*)&Bl[srow * ASTR + skq + 8] = bl1;
        __syncthreads();

        short8_t afh[4], afl[4], bfh[4], bfl[4];
#pragma unroll
        for (int t = 0; t < 4; ++t) {
            const int m = wm * 64 + t * 16 + l16;
            afh[t] = *(const short8_t*)&Ah[m * ASTR + quad * 8];
            afl[t] = *(const short8_t*)&Al[m * ASTR + quad * 8];
            const int n = wn * 64 + t * 16 + l16;
            bfh[t] = *(const short8_t*)&Bh[n * ASTR + quad * 8];
            bfl[t] = *(const short8_t*)&Bl[n * ASTR + quad * 8];
        }
#pragma unroll
        for (int i = 0; i < 4; ++i)
#pragma unroll
            for (int j = 0; j < 4; ++j) {
                acc[i][j] = __builtin_amdgcn_mfma_f32_16x16x32_bf16(afh[i], bfh[j], acc[i][j], 0, 0, 0);
                acc[i][j] = __builtin_amdgcn_mfma_f32_16x16x32_bf16(afh[i], bfl[j], acc[i][j], 0, 0, 0);
                acc[i][j] = __builtin_amdgcn_mfma_f32_16x16x32_bf16(afl[i], bfh[j], acc[i][j], 0, 0, 0);
            }
    }

#pragma unroll
    for (int j = 0; j < 4; ++j) {
        const int col = bn + wn * 64 + j * 16 + l16;
        if (col >= Ncol) continue;
        const float bv = bias ? bias[col] : 0.0f;
#pragma unroll
        for (int i = 0; i < 4; ++i) {
#pragma unroll
            for (int r = 0; r < 4; ++r) {
                const int row = bm + wm * 64 + i * 16 + quad * 4 + r;
                if (row >= M) continue;
                float v = acc[i][j][r] + bv;
                if (act) v = softplusf(v);
                C[(size_t)row * ldc + col] = v;
            }
        }
    }
}

// fp32 GEMM (used only for layer 2, K=48)
__global__ __launch_bounds__(256) void k_gemm(
    const float* __restrict__ A, int lda,
    const float* __restrict__ B, int ldb,
    float* __restrict__ C, int ldc,
    int M, int K, int Ncol,
    const float* __restrict__ bias, int act)
{
    __shared__ float As[16][128];
    __shared__ float Bs[16][128];
    const int tid = threadIdx.x;
    const int tx = tid & 15;
    const int ty = tid >> 4;
    const int bm = blockIdx.y * 128;
    const int bn = blockIdx.x * 128;
    const int arow = tid >> 1;
    const int akq = (tid & 1) * 8;
    const int bkr = tid >> 4;
    const int bcq = (tid & 15) * 8;

    float acc[8][8];
#pragma unroll
    for (int i = 0; i < 8; ++i)
#pragma unroll
        for (int j = 0; j < 8; ++j) acc[i][j] = 0.0f;

    for (int k0 = 0; k0 < K; k0 += 16) {
        float4 a0 = make_float4(0, 0, 0, 0), a1 = make_float4(0, 0, 0, 0);
        int gr = bm + arow;
        if (gr < M) {
            a0 = *(const float4*)(A + gr * lda + k0 + akq);
            a1 = *(const float4*)(A + gr * lda + k0 + akq + 4);
        }
        float4 b0 = make_float4(0, 0, 0, 0), b1 = make_float4(0, 0, 0, 0);
        int cb = bn + bcq;
        const float* Bp = B + (k0 + bkr) * ldb;
        if (cb < Ncol)     b0 = *(const float4*)(Bp + cb);
        if (cb + 4 < Ncol) b1 = *(const float4*)(Bp + cb + 4);
        __syncthreads();
        As[akq + 0][arow] = a0.x; As[akq + 1][arow] = a0.y;
        As[akq + 2][arow] = a0.z; As[akq + 3][arow] = a0.w;
        As[akq + 4][arow] = a1.x; As[akq + 5][arow] = a1.y;
        As[akq + 6][arow] = a1.z; As[akq + 7][arow] = a1.w;
        *(float4*)&Bs[bkr][bcq] = b0;
        *(float4*)&Bs[bkr][bcq + 4] = b1;
        __syncthreads();
#pragma unroll
        for (int kk = 0; kk < 16; ++kk) {
            float a[8], b[8];
            float4 t;
            t = *(const float4*)&As[kk][ty * 4];      a[0] = t.x; a[1] = t.y; a[2] = t.z; a[3] = t.w;
            t = *(const float4*)&As[kk][64 + ty * 4]; a[4] = t.x; a[5] = t.y; a[6] = t.z; a[7] = t.w;
            t = *(const float4*)&Bs[kk][tx * 4];      b[0] = t.x; b[1] = t.y; b[2] = t.z; b[3] = t.w;
            t = *(const float4*)&Bs[kk][64 + tx * 4]; b[4] = t.x; b[5] = t.y; b[6] = t.z; b[7] = t.w;
#pragma unroll
            for (int i = 0; i < 8; ++i)
#pragma unroll
                for (int j = 0; j < 8; ++j)
                    acc[i][j] = fmaf(a[i], b[j], acc[i][j]);
        }
    }
#pragma unroll
    for (int i = 0; i < 8; ++i) {
        int r = bm + ((i < 4) ? (ty * 4 + i) : (64 + ty * 4 + i - 4));
        if (r >= M) continue;
#pragma unroll
        for (int j = 0; j < 8; ++j) {
            int cl = bn + ((j < 4) ? (tx * 4 + j) : (64 + tx * 4 + j - 4));
            if (cl >= Ncol) continue;
            float v = acc[i][j];
            if (bias) v += bias[cl];
            if (act) v = softplusf(v);
            C[r * ldc + cl] = v;
        }
    }
}

// CSR propagation with x4 edge-loop unroll for gather ILP.
__global__ __launch_bounds__(256) void k_prop(
    const int* __restrict__ rowptr, const int* __restrict__ ccol,
    const float* __restrict__ cw,
    const float* __restrict__ z, int zld, int zoff,
    float* __restrict__ out, int outld, int ooff,
    int ltw, float alpha,
    const float* __restrict__ add1, int a1ld, int a1off, float c1,
    const float* __restrict__ add2, int a2ld, int a2off,
    const float* __restrict__ bias, int act)
{
    const int T = 1 << ltw;
    const int lane = threadIdx.x & (T - 1);
    const int node = blockIdx.x * (256 >> ltw) + (threadIdx.x >> ltw);
    if (node >= NN) return;
    const int f4 = lane * 4;
    const int s = rowptr[node];
    const int e = rowptr[node + 1];
    float ax = 0, ay = 0, az = 0, aw = 0;
    float bx = 0, by = 0, bz = 0, bw = 0;
    const float* zp = z + zoff + f4;
    int p = s;
    for (; p + 4 <= e; p += 4) {
        int c0 = ccol[p + 0], c1i = ccol[p + 1], c2 = ccol[p + 2], c3 = ccol[p + 3];
        float w0 = cw[p + 0], w1 = cw[p + 1], w2 = cw[p + 2], w3 = cw[p + 3];
        const float4 z0 = *(const float4*)(zp + (size_t)c0 * zld);
        const float4 z1 = *(const float4*)(zp + (size_t)c1i * zld);
        const float4 z2 = *(const float4*)(zp + (size_t)c2 * zld);
        const float4 z3 = *(const float4*)(zp + (size_t)c3 * zld);
        ax = fmaf(w0, z0.x, ax); ay = fmaf(w0, z0.y, ay); az = fmaf(w0, z0.z, az); aw = fmaf(w0, z0.w, aw);
        bx = fmaf(w1, z1.x, bx); by = fmaf(w1, z1.y, by); bz = fmaf(w1, z1.z, bz); bw = fmaf(w1, z1.w, bw);
        ax = fmaf(w2, z2.x, ax); ay = fmaf(w2, z2.y, ay); az = fmaf(w2, z2.z, az); aw = fmaf(w2, z2.w, aw);
        bx = fmaf(w3, z3.x, bx); by = fmaf(w3, z3.y, by); bz = fmaf(w3, z3.z, bz); bw = fmaf(w3, z3.w, bw);
    }
    for (; p < e; ++p) {
        int c = ccol[p];
        float wv = cw[p];
        const float4 zv = *(const float4*)(zp + (size_t)c * zld);
        ax = fmaf(wv, zv.x, ax); ay = fmaf(wv, zv.y, ay);
        az = fmaf(wv, zv.z, az); aw = fmaf(wv, zv.w, aw);
    }
    ax += bx; ay += by; az += bz; aw += bw;
    ax *= alpha; ay *= alpha; az *= alpha; aw *= alpha;
    if (add1) {
        const float4 t = *(const float4*)(add1 + (size_t)node * a1ld + a1off + f4);
        ax = fmaf(c1, t.x, ax); ay = fmaf(c1, t.y, ay);
        az = fmaf(c1, t.z, az); aw = fmaf(c1, t.w, aw);
    }
    if (add2) {
        const float4 t = *(const float4*)(add2 + (size_t)node * a2ld + a2off + f4);
        ax += t.x; ay += t.y; az += t.z; aw += t.w;
    }
    if (bias) {
        const float4 t = *(const float4*)(bias + f4);
        ax += t.x; ay += t.y; az += t.z; aw += t.w;
    }
    if (act) { ax = softplusf(ax); ay = softplusf(ay); az = softplusf(az); aw = softplusf(aw); }
    float4 o; o.x = ax; o.y = ay; o.z = az; o.w = aw;
    *(float4*)(out + (size_t)node * outld + ooff + f4) = o;
}

__global__ __launch_bounds__(256) void k_bnstats(const float* __restrict__ h, int ld, int lc,
                                                 float* __restrict__ stats) {
    const int C = 1 << lc;
    const int tid = threadIdx.x;
    const int c = tid & (C - 1);
    const int rpb = 256 >> lc;
    int r = blockIdx.x * rpb + (tid >> lc);
    const int stride = gridDim.x * rpb;
    float s = 0.0f, q = 0.0f;
    for (; r < NN; r += stride) {
        float v = h[r * ld + c];
        s += v;
        q = fmaf(v, v, q);
    }
    __shared__ float shs[256], shq[256];
    shs[tid] = s; shq[tid] = q;
    __syncthreads();
    for (int o = 128; o >= C; o >>= 1) {
        if (tid < o) { shs[tid] += shs[tid + o]; shq[tid] += shq[tid + o]; }
        __syncthreads();
    }
    if (tid < C) {
        atomicAdd(&stats[c], shs[tid]);
        atomicAdd(&stats[128 + c], shq[tid]);
    }
}

__global__ void k_bnapply(float* __restrict__ h, int ld, int lc,
                          const float* __restrict__ stats,
                          const float* __restrict__ g, const float* __restrict__ be) {
    int idx = blockIdx.x * 256 + threadIdx.x;
    if (idx >= (NN << lc)) return;
    int c = idx & ((1 << lc) - 1);
    int r = idx >> lc;
    const float invN = 1.0f / (float)NN;
    float m = stats[c] * invN;
    float var = fmaf(stats[128 + c], invN, -m * m);
    var = fmaxf(var, 0.0f);
    float inv = rsqrtf(var + 1e-5f);
    float v = h[r * ld + c];
    h[r * ld + c] = fmaf(g[c] * inv, v - m, be[c]);
}

static __device__ __forceinline__ int lower_bound_dev(const int* __restrict__ b, int val) {
    int lo = 0, hi = NN;
    while (lo < hi) {
        int mid = (lo + hi) >> 1;
        if (b[mid] < val) lo = mid + 1; else hi = mid;
    }
    return lo;
}

__global__ void k_gbounds(const int* __restrict__ batch, int* __restrict__ gb) {
    int g = threadIdx.x;
    if (g <= NG) gb[g] = (g == NG) ? NN : lower_bound_dev(batch, g);
}

__global__ __launch_bounds__(256) void k_pool1(const float* __restrict__ h,
                                               const int* __restrict__ gb,
                                               float* __restrict__ partial) {
    int g = blockIdx.y;
    int j = blockIdx.x;
    int start = gb[g], end = gb[g + 1];
    int len = end - start;
    int chunk = (len + 15) >> 4;
    int s = start + j * chunk;
    int e = min(s + chunk, end);
    int c = threadIdx.x;
    float mx = -INFINITY, sum = 0.0f;
    for (int r = s; r < e; ++r) {
        float v = h[(size_t)r * 256 + c];
        mx = fmaxf(mx, v);
        sum += v;
    }
    size_t base = ((size_t)(g * 16 + j)) * 512;
    partial[base + c] = mx;
    partial[base + 256 + c] = sum;
}

__global__ __launch_bounds__(256) void k_pool2(const float* __restrict__ partial,
                                               const int* __restrict__ gb,
                                               float* __restrict__ pooled) {
    int g = blockIdx.x;
    int c = threadIdx.x;
    float mx = -INFINITY, sum = 0.0f;
#pragma unroll
    for (int j = 0; j < 16; ++j) {
        size_t base = ((size_t)(g * 16 + j)) * 512;
        mx = fmaxf(mx, partial[base + c]);
        sum += partial[base + 256 + c];
    }
    int len = gb[g + 1] - gb[g];
    pooled[g * 512 + c] = (len > 0) ? mx : 0.0f;
    pooled[g * 512 + 256 + c] = sum / fmaxf((float)len, 1.0f);
}

__global__ __launch_bounds__(64) void k_dense(const float* __restrict__ pooled,
                                              const float* __restrict__ Wd,
                                              const float* __restrict__ bd,
                                              float* __restrict__ out) {
    int g = blockIdx.x;
    int t = threadIdx.x;
    float p0 = 0, p1 = 0, p2 = 0, p3 = 0;
    for (int k = t; k < 512; k += 64) {
        float pv = pooled[g * 512 + k];
        p0 = fmaf(pv, Wd[k * 4 + 0], p0);
        p1 = fmaf(pv, Wd[k * 4 + 1], p1);
        p2 = fmaf(pv, Wd[k * 4 + 2], p2);
        p3 = fmaf(pv, Wd[k * 4 + 3], p3);
    }
#pragma unroll
    for (int o = 32; o > 0; o >>= 1) {
        p0 += __shfl_down(p0, o);
        p1 += __shfl_down(p1, o);
        p2 += __shfl_down(p2, o);
        p3 += __shfl_down(p3, o);
    }
    if (t == 0) {
        float l0 = p0 + bd[0], l1 = p1 + bd[1], l2 = p2 + bd[2], l3 = p3 + bd[3];
        float m = fmaxf(fmaxf(l0, l1), fmaxf(l2, l3));
        float ls = m + logf(expf(l0 - m) + expf(l1 - m) + expf(l2 - m) + expf(l3 - m));
        out[g * 4 + 0] = l0 - ls;
        out[g * 4 + 1] = l1 - ls;
        out[g * 4 + 2] = l2 - ls;
        out[g * 4 + 3] = l3 - ls;
    }
}

extern "C" void kernel_launch(void* const* d_in, const int* in_sizes, int n_in,
                              void* d_out, int out_size, void* d_ws, size_t ws_size,
                              hipStream_t stream)
{
    const float* x    = (const float*)d_in[0];
    const float* ew   = (const float*)d_in[1];
    const int*   row  = (const int*)d_in[2];
    const int*   colp = row + NE;
    const int*   batch = (const int*)d_in[3];
    const float* W1 = (const float*)d_in[4];
    const float* b1 = (const float*)d_in[5];
    const float* g1 = (const float*)d_in[6];
    const float* be1 = (const float*)d_in[7];
    const float* W2 = (const float*)d_in[8];
    const float* b2 = (const float*)d_in[9];
    const float* g2 = (const float*)d_in[10];
    const float* be2 = (const float*)d_in[11];
    const float* W3 = (const float*)d_in[12];
    const float* b3 = (const float*)d_in[13];
    const float* g3 = (const float*)d_in[14];
    const float* be3 = (const float*)d_in[15];
    const float* W4 = (const float*)d_in[16];
    const float* b4 = (const float*)d_in[17];
    const float* g4 = (const float*)d_in[18];
    const float* be4 = (const float*)d_in[19];
    const float* W5 = (const float*)d_in[20];
    const float* b5 = (const float*)d_in[21];
    const float* Wd = (const float*)d_in[22];
    const float* bd = (const float*)d_in[23];
    float* outp = (float*)d_out;
    (void)in_sizes; (void)n_in; (void)out_size; (void)ws_size;

    char* wsb = (char*)d_ws;
    size_t off = 0;
    auto take = [&](size_t bytes) -> void* {
        void* p = wsb + off;
        off = (off + bytes + 255) & ~(size_t)255;
        return p;
    };
    int*   rowptr = (int*)take((NN + 1) * sizeof(int));
    int*   cnt    = (int*)take((size_t)NN * sizeof(int));
    int*   cursor = (int*)take((size_t)NN * sizeof(int));
    float* deg    = (float*)take((size_t)NN * sizeof(float));
    int*   bsum   = (int*)take(256 * sizeof(int));
    int*   gb     = (int*)take((NG + 1) * sizeof(int));
    int*   ccol   = (int*)take((size_t)NE * sizeof(int));
    float* cw     = (float*)take((size_t)NE * sizeof(float));
    float* stats  = (float*)take(256 * sizeof(float));
    float* wcat   = (float*)take(6144 * sizeof(float));
    unsigned short* bt1h = (unsigned short*)take(48 * 128 * 2);
    unsigned short* bt1l = (unsigned short*)take(48 * 128 * 2);
    unsigned short* bt3h = (unsigned short*)take(64 * 96 * 2);
    unsigned short* bt3l = (unsigned short*)take(64 * 96 * 2);
    unsigned short* bt4h = (unsigned short*)take(128 * 192 * 2);
    unsigned short* bt4l = (unsigned short*)take(128 * 192 * 2);
    unsigned short* bt5h = (unsigned short*)take(256 * 384 * 2);
    unsigned short* bt5l = (unsigned short*)take(256 * 384 * 2);
    float* partial= (float*)take((size_t)NG * 16 * 512 * sizeof(float));
    float* pooled = (float*)take((size_t)NG * 512 * sizeof(float));
    float* bufA   = (float*)take((size_t)NN * 384 * sizeof(float));
    float* bufB   = (float*)take((size_t)NN * 256 * sizeof(float));

    float* P   = bufA;                        // (NN,48) layer-1 pre-transformed
    float* Hc3 = bufA;                        // (NN,96)
    float* Hc5 = bufA;                        // (NN,384)
    float* u   = bufB;                        // (NN,16)
    float* vv  = bufB + (size_t)NN * 16;      // (NN,16)
    float* Hc2 = bufB + (size_t)NN * 32;      // (NN,48)
    float* Hc4 = bufB;                        // (NN,192)
    float* h5  = bufB;                        // (NN,256)

    hipMemsetAsync(deg, 0, NN * sizeof(float), stream);
    hipMemsetAsync(cnt, 0, NN * sizeof(int), stream);
    hipMemsetAsync(cursor, 0, NN * sizeof(int), stream);

    k_deg_hist<<<6250, 256, 0, stream>>>(row, ew, deg, cnt);
    k_dinv<<<196, 256, 0, stream>>>(deg);
    k_scan1<<<196, 256, 0, stream>>>(cnt, rowptr, bsum);
    k_scan2<<<1, 256, 0, stream>>>(bsum, 196);
    k_scan3<<<196, 256, 0, stream>>>(rowptr, bsum);
    k_scatter<<<6250, 256, 0, stream>>>(row, colp, ew, rowptr, cursor, deg, ccol, cw);
    k_wcat1<<<24, 256, 0, stream>>>(W1, wcat);
    k_gbounds<<<1, 128, 0, stream>>>(batch, gb);
    k_wsplit<<<24, 256, 0, stream>>>(wcat, 128, 48, bt1h, bt1l);
    k_wsplit<<<24, 256, 0, stream>>>(W3, 96, 64, bt3h, bt3l);
    k_wsplit<<<96, 256, 0, stream>>>(W4, 192, 128, bt4h, bt4l);
    k_wsplit<<<384, 256, 0, stream>>>(W5, 384, 256, bt5h, bt5l);

    // ---- Layer 1 (128 -> 16), transformed: out = P0 + prop(P1) + 2*prop(prop(P2)) + b
    k_gemm_mfma<<<dim3(1, 391), 256, 0, stream>>>(x, 128, bt1h, bt1l, P, 48, NN, 128, 48, nullptr, 0);
    k_prop<<<782, 256, 0, stream>>>(rowptr, ccol, cw, P, 48, 16, u, 16, 0, 2, 1.0f,
                                    nullptr, 0, 0, 0.0f, nullptr, 0, 0, nullptr, 0);
    k_prop<<<782, 256, 0, stream>>>(rowptr, ccol, cw, P, 48, 32, vv, 16, 0, 2, 1.0f,
                                    nullptr, 0, 0, 0.0f, nullptr, 0, 0, nullptr, 0);
    k_prop<<<782, 256, 0, stream>>>(rowptr, ccol, cw, vv, 16, 0, Hc2, 48, 0, 2, 2.0f,
                                    P, 48, 0, 1.0f, u, 16, 0, b1, 1);
    hipMemsetAsync(stats, 0, 1024, stream);
    k_bnstats<<<256, 256, 0, stream>>>(Hc2, 48, 4, stats);
    k_bnapply<<<(NN * 16 + 255) / 256, 256, 0, stream>>>(Hc2, 48, 4, stats, g1, be1);

    // ---- Layer 2 (16 -> 32)
    k_prop<<<782, 256, 0, stream>>>(rowptr, ccol, cw, Hc2, 48, 0, Hc2, 48, 16, 2, 1.0f,
                                    nullptr, 0, 0, 0.0f, nullptr, 0, 0, nullptr, 0);
    k_prop<<<782, 256, 0, stream>>>(rowptr, ccol, cw, Hc2, 48, 16, Hc2, 48, 32, 2, 2.0f,
                                    Hc2, 48, 0, -1.0f, nullptr, 0, 0, nullptr, 0);
    k_gemm<<<dim3(1, 391), 256, 0, stream>>>(Hc2, 48, W2, 32, Hc3, 96, NN, 48, 32, b2, 1);
    hipMemsetAsync(stats, 0, 1024, stream);
    k_bnstats<<<256, 256, 0, stream>>>(Hc3, 96, 5, stats);
    k_bnapply<<<(NN * 32 + 255) / 256, 256, 0, stream>>>(Hc3, 96, 5, stats, g2, be2);

    // ---- Layer 3 (32 -> 64)
    k_prop<<<1563, 256, 0, stream>>>(rowptr, ccol, cw, Hc3, 96, 0, Hc3, 96, 32, 3, 1.0f,
                                     nullptr, 0, 0, 0.0f, nullptr, 0, 0, nullptr, 0);
    k_prop<<<1563, 256, 0, stream>>>(rowptr, ccol, cw, Hc3, 96, 32, Hc3, 96, 64, 3, 2.0f,
                                     Hc3, 96, 0, -1.0f, nullptr, 0, 0, nullptr, 0);
    k_gemm_mfma<<<dim3(1, 391), 256, 0, stream>>>(Hc3, 96, bt3h, bt3l, Hc4, 192, NN, 96, 64, b3, 1);
    hipMemsetAsync(stats, 0, 1024, stream);
    k_bnstats<<<256, 256, 0, stream>>>(Hc4, 192, 6, stats);
    k_bnapply<<<(NN * 64 + 255) / 256, 256, 0, stream>>>(Hc4, 192, 6, stats, g3, be3);

    // ---- Layer 4 (64 -> 128)
    k_prop<<<3125, 256, 0, stream>>>(rowptr, ccol, cw, Hc4, 192, 0, Hc4, 192, 64, 4, 1.0f,
                                     nullptr, 0, 0, 0.0f, nullptr, 0, 0, nullptr, 0);
    k_prop<<<3125, 256, 0, stream>>>(rowptr, ccol, cw, Hc4, 192, 64, Hc4, 192, 128, 4, 2.0f,
                                     Hc4, 192, 0, -1.0f, nullptr, 0, 0, nullptr, 0);
    k_gemm_mfma<<<dim3(1, 391), 256, 0, stream>>>(Hc4, 192, bt4h, bt4l, Hc5, 384, NN, 192, 128, b4, 1);
    hipMemsetAsync(stats, 0, 1024, stream);
    k_bnstats<<<256, 256, 0, stream>>>(Hc5, 384, 7, stats);
    k_bnapply<<<(NN * 128 + 255) / 256, 256, 0, stream>>>(Hc5, 384, 7, stats, g4, be4);

    // ---- Layer 5 (128 -> 256), no BN/act
    k_prop<<<6250, 256, 0, stream>>>(rowptr, ccol, cw, Hc5, 384, 0, Hc5, 384, 128, 5, 1.0f,
                                     nullptr, 0, 0, 0.0f, nullptr, 0, 0, nullptr, 0);
    k_prop<<<6250, 256, 0, stream>>>(rowptr, ccol, cw, Hc5, 384, 128, Hc5, 384, 256, 5, 2.0f,
                                     Hc5, 384, 0, -1.0f, nullptr, 0, 0, nullptr, 0);
    k_gemm_mfma<<<dim3(2, 391), 256, 0, stream>>>(Hc5, 384, bt5h, bt5l, h5, 256, NN, 384, 256, b5, 0);

    // ---- Pool + dense + log_softmax
    k_pool1<<<dim3(16, 64), 256, 0, stream>>>(h5, gb, partial);
    k_pool2<<<64, 256, 0, stream>>>(partial, gb, pooled);
    k_dense<<<64, 64, 0, stream>>>(pooled, Wd, bd, outp);
}

// Round 4
// 1229.220 us; speedup vs baseline: 1.3821x; 1.0120x over previous
//
#include <hip/hip_runtime.h>
#include <cmath>

#define NN 50000
#define NE 1600000
#define NG 64
#define CAP 96   // slots per row; deg ~ Poisson(32), P(deg>=96) ~ e^-41 -> safe

typedef __attribute__((ext_vector_type(8))) short short8_t;
typedef __attribute__((ext_vector_type(4))) float floatx4;

static __device__ __forceinline__ float softplusf(float x) {
    return fmaxf(x, 0.0f) + log1pf(expf(-fabsf(x)));
}

// exact split x = hi + lo (bf16 each, ~2^-16 relative residual)
static __device__ __forceinline__ void split_bf16(float x, unsigned short& hi, unsigned short& lo) {
    unsigned u = __float_as_uint(x);
    unsigned hb = u & 0xFFFF0000u;
    hi = (unsigned short)(hb >> 16);
    float r = x - __uint_as_float(hb);   // exact
    unsigned v = __float_as_uint(r);
    unsigned t = (v >> 16) & 1u;
    lo = (unsigned short)((v + 0x7FFFu + t) >> 16);  // RNE
}

// Single-pass slotted CSR build: 1 atomic + one 8B store per edge.
__global__ void k_slot(const int* __restrict__ row, const int* __restrict__ col,
                       const float* __restrict__ w,
                       int* __restrict__ cnt, int2* __restrict__ slots) {
    int e = blockIdx.x * blockDim.x + threadIdx.x;
    if (e < NE) {
        int r = row[e];
        int k = atomicAdd(&cnt[r], 1);
        k = min(k, CAP - 1);  // defensive; never hit for this degree distribution
        slots[(size_t)r * CAP + k] = make_int2(col[e], __float_as_int(w[e]));
    }
}

// deg[r] = sum of raw w over row r (atomic-free, 16 lanes per node)
__global__ __launch_bounds__(256) void k_degsum(const int* __restrict__ cnt,
                                                const int2* __restrict__ slots,
                                                float* __restrict__ deg) {
    int tid = threadIdx.x;
    int lane = tid & 15;
    int node = blockIdx.x * 16 + (tid >> 4);
    if (node >= NN) return;
    int e = cnt[node];
    const int2* base = slots + (size_t)node * CAP;
    float s = 0.0f;
    for (int k = lane; k < e; k += 16) s += __int_as_float(base[k].y);
#pragma unroll
    for (int m = 8; m >= 1; m >>= 1) s += __shfl_xor(s, m);
    if (lane == 0) deg[node] = s;
}

__global__ void k_dinv(float* __restrict__ deg) {
    int i = blockIdx.x * blockDim.x + threadIdx.x;
    if (i < NN) {
        float d = deg[i];
        deg[i] = (d > 0.0f) ? rsqrtf(d) : 0.0f;
    }
}

// In-place: slot.y = -w * dinv[r] * dinv[col]
__global__ __launch_bounds__(256) void k_rescale(const int* __restrict__ cnt,
                                                 int2* __restrict__ slots,
                                                 const float* __restrict__ dinv) {
    int tid = threadIdx.x;
    int lane = tid & 15;
    int node = blockIdx.x * 16 + (tid >> 4);
    if (node >= NN) return;
    int e = cnt[node];
    float dr = dinv[node];
    int2* base = slots + (size_t)node * CAP;
    for (int k = lane; k < e; k += 16) {
        int2 s = base[k];
        float wv = __int_as_float(s.y);
        base[k].y = __float_as_int(-wv * dr * dinv[s.x]);
    }
}

// Wcat1 (128 x 48) = [W0-W2 | W1 | W2] from W1 input (3,128,16)
__global__ void k_wcat1(const float* __restrict__ W1, float* __restrict__ wc) {
    int i = blockIdx.x * blockDim.x + threadIdx.x;
    if (i < 128 * 48) {
        int k = i / 48, j = i - k * 48;
        float v;
        if (j < 16)      v = W1[k * 16 + j] - W1[2 * 2048 + k * 16 + j];
        else if (j < 32) v = W1[2048 + k * 16 + (j - 16)];
        else             v = W1[2 * 2048 + k * 16 + (j - 32)];
        wc[i] = v;
    }
}

// Split W (K,N) fp32 into transposed hi/lo bf16: hiT/loT are (N,K)
__global__ void k_wsplit(const float* __restrict__ W, int K, int N,
                         unsigned short* __restrict__ hiT, unsigned short* __restrict__ loT) {
    int idx = blockIdx.x * 256 + threadIdx.x;
    if (idx < K * N) {
        int k = idx / N, n = idx - k * N;
        unsigned short h, l;
        split_bf16(W[idx], h, l);
        hiT[(size_t)n * K + k] = h;
        loT[(size_t)n * K + k] = l;
    }
}

// ---------------- MFMA split-bf16 GEMM ----------------
#define ASTR 40  // padded LDS row stride in ushorts (32 + 8)

__global__ __launch_bounds__(256, 2) void k_gemm_mfma(
    const float* __restrict__ A, int lda,
    const unsigned short* __restrict__ BhiT,
    const unsigned short* __restrict__ BloT,
    float* __restrict__ C, int ldc,
    int M, int K, int Ncol,
    const float* __restrict__ bias, int act)
{
    __shared__ unsigned short Ah[128 * ASTR];
    __shared__ unsigned short Al[128 * ASTR];
    __shared__ unsigned short Bh[128 * ASTR];
    __shared__ unsigned short Bl[128 * ASTR];

    const int tid = threadIdx.x;
    const int lane = tid & 63;
    const int wave = tid >> 6;
    const int wm = wave >> 1, wn = wave & 1;
    const int quad = lane >> 4, l16 = lane & 15;
    const int bm = blockIdx.y * 128, bn = blockIdx.x * 128;

    const int srow = tid >> 1;        // 0..127
    const int skq  = (tid & 1) * 16;  // 0 or 16

    floatx4 acc[4][4];
#pragma unroll
    for (int i = 0; i < 4; ++i)
#pragma unroll
        for (int j = 0; j < 4; ++j) acc[i][j] = (floatx4){0.f, 0.f, 0.f, 0.f};

    for (int k0 = 0; k0 < K; k0 += 32) {
        float4 a0 = make_float4(0, 0, 0, 0), a1 = a0, a2 = a0, a3 = a0;
        const int ga = bm + srow;
        if (ga < M) {
            const float* Ap = A + (size_t)ga * lda + k0 + skq;
            a0 = *(const float4*)(Ap + 0);
            a1 = *(const float4*)(Ap + 4);
            a2 = *(const float4*)(Ap + 8);
            a3 = *(const float4*)(Ap + 12);
        }
        uint4 bh0 = make_uint4(0, 0, 0, 0), bh1 = bh0, bl0 = bh0, bl1 = bh0;
        const int gb = bn + srow;
        if (gb < Ncol) {
            const unsigned short* ph = BhiT + (size_t)gb * K + k0 + skq;
            const unsigned short* pl = BloT + (size_t)gb * K + k0 + skq;
            bh0 = *(const uint4*)(ph);
            bh1 = *(const uint4*)(ph + 8);
            bl0 = *(const uint4*)(pl);
            bl1 = *(const uint4*)(pl + 8);
        }
        __attribute__((aligned(16))) unsigned short ah[16], al[16];
        const float av[16] = {a0.x, a0.y, a0.z, a0.w, a1.x, a1.y, a1.z, a1.w,
                              a2.x, a2.y, a2.z, a2.w, a3.x, a3.y, a3.z, a3.w};
#pragma unroll
        for (int i = 0; i < 16; ++i) split_bf16(av[i], ah[i], al[i]);

        __syncthreads();
        *(uint4*)&Ah[srow * ASTR + skq]     = *(const uint4*)&ah[0];
        *(uint4*)&Ah[srow * ASTR + skq + 8] = *(const uint4*)&ah[8];
        *(uint4*)&Al[srow * ASTR + skq]     = *(const uint4*)&al[0];
        *(uint4*)&Al[srow * ASTR + skq + 8] = *(const uint4*)&al[8];
        *(uint4*)&Bh[srow * ASTR + skq]     = bh0;
        *(uint4*)&Bh[srow * ASTR + skq + 8] = bh1;
        *(uint4*)&Bl[srow * ASTR + skq]     = bl0;
        *(uint4*)&Bl[srow * ASTR + skq + 8] = bl1;
        __syncthreads();

        short8_t afh[4], afl[4], bfh[4], bfl[4];
#pragma unroll
        for (int t = 0; t < 4; ++t) {
            const int m = wm * 64 + t * 16 + l16;
            afh[t] = *(const short8_t*)&Ah[m * ASTR + quad * 8];
            afl[t] = *(const short8_t*)&Al[m * ASTR + quad * 8];
            const int n = wn * 64 + t * 16 + l16;
            bfh[t] = *(const short8_t*)&Bh[n * ASTR + quad * 8];
            bfl[t] = *(const short8_t*)&Bl[n * ASTR + quad * 8];
        }
#pragma unroll
        for (int i = 0; i < 4; ++i)
#pragma unroll
            for (int j = 0; j < 4; ++j) {
                acc[i][j] = __builtin_amdgcn_mfma_f32_16x16x32_bf16(afh[i], bfh[j], acc[i][j], 0, 0, 0);
                acc[i][j] = __builtin_amdgcn_mfma_f32_16x16x32_bf16(afh[i], bfl[j], acc[i][j], 0, 0, 0);
                acc[i][j] = __builtin_amdgcn_mfma_f32_16x16x32_bf16(afl[i], bfh[j], acc[i][j], 0, 0, 0);
            }
    }

#pragma unroll
    for (int j = 0; j < 4; ++j) {
        const int col = bn + wn * 64 + j * 16 + l16;
        if (col >= Ncol) continue;
        const float bv = bias ? bias[col] : 0.0f;
#pragma unroll
        for (int i = 0; i < 4; ++i) {
#pragma unroll
            for (int r = 0; r < 4; ++r) {
                const int row = bm + wm * 64 + i * 16 + quad * 4 + r;
                if (row >= M) continue;
                float v = acc[i][j][r] + bv;
                if (act) v = softplusf(v);
                C[(size_t)row * ldc + col] = v;
            }
        }
    }
}

// fp32 GEMM (used only for layer 2, K=48)
__global__ __launch_bounds__(256) void k_gemm(
    const float* __restrict__ A, int lda,
    const float* __restrict__ B, int ldb,
    float* __restrict__ C, int ldc,
    int M, int K, int Ncol,
    const float* __restrict__ bias, int act)
{
    __shared__ float As[16][128];
    __shared__ float Bs[16][128];
    const int tid = threadIdx.x;
    const int tx = tid & 15;
    const int ty = tid >> 4;
    const int bm = blockIdx.y * 128;
    const int bn = blockIdx.x * 128;
    const int arow = tid >> 1;
    const int akq = (tid & 1) * 8;
    const int bkr = tid >> 4;
    const int bcq = (tid & 15) * 8;

    float acc[8][8];
#pragma unroll
    for (int i = 0; i < 8; ++i)
#pragma unroll
        for (int j = 0; j < 8; ++j) acc[i][j] = 0.0f;

    for (int k0 = 0; k0 < K; k0 += 16) {
        float4 a0 = make_float4(0, 0, 0, 0), a1 = make_float4(0, 0, 0, 0);
        int gr = bm + arow;
        if (gr < M) {
            a0 = *(const float4*)(A + gr * lda + k0 + akq);
            a1 = *(const float4*)(A + gr * lda + k0 + akq + 4);
        }
        float4 b0 = make_float4(0, 0, 0, 0), b1 = make_float4(0, 0, 0, 0);
        int cb = bn + bcq;
        const float* Bp = B + (k0 + bkr) * ldb;
        if (cb < Ncol)     b0 = *(const float4*)(Bp + cb);
        if (cb + 4 < Ncol) b1 = *(const float4*)(Bp + cb + 4);
        __syncthreads();
        As[akq + 0][arow] = a0.x; As[akq + 1][arow] = a0.y;
        As[akq + 2][arow] = a0.z; As[akq + 3][arow] = a0.w;
        As[akq + 4][arow] = a1.x; As[akq + 5][arow] = a1.y;
        As[akq + 6][arow] = a1.z; As[akq + 7][arow] = a1.w;
        *(float4*)&Bs[bkr][bcq] = b0;
        *(float4*)&Bs[bkr][bcq + 4] = b1;
        __syncthreads();
#pragma unroll
        for (int kk = 0; kk < 16; ++kk) {
            float a[8], b[8];
            float4 t;
            t = *(const float4*)&As[kk][ty * 4];      a[0] = t.x; a[1] = t.y; a[2] = t.z; a[3] = t.w;
            t = *(const float4*)&As[kk][64 + ty * 4]; a[4] = t.x; a[5] = t.y; a[6] = t.z; a[7] = t.w;
            t = *(const float4*)&Bs[kk][tx * 4];      b[0] = t.x; b[1] = t.y; b[2] = t.z; b[3] = t.w;
            t = *(const float4*)&Bs[kk][64 + tx * 4]; b[4] = t.x; b[5] = t.y; b[6] = t.z; b[7] = t.w;
#pragma unroll
            for (int i = 0; i < 8; ++i)
#pragma unroll
                for (int j = 0; j < 8; ++j)
                    acc[i][j] = fmaf(a[i], b[j], acc[i][j]);
        }
    }
#pragma unroll
    for (int i = 0; i < 8; ++i) {
        int r = bm + ((i < 4) ? (ty * 4 + i) : (64 + ty * 4 + i - 4));
        if (r >= M) continue;
#pragma unroll
        for (int j = 0; j < 8; ++j) {
            int cl = bn + ((j < 4) ? (tx * 4 + j) : (64 + tx * 4 + j - 4));
            if (cl >= Ncol) continue;
            float v = acc[i][j];
            if (bias) v += bias[cl];
            if (act) v = softplusf(v);
            C[r * ldc + cl] = v;
        }
    }
}

// Slotted propagation: out[i,:] = alpha * sum_k slots[i][k].w * z[slots[i][k].col, :] (+ extras)
__global__ __launch_bounds__(256) void k_prop(
    const int* __restrict__ cnt, const int2* __restrict__ slots,
    const float* __restrict__ z, int zld, int zoff,
    float* __restrict__ out, int outld, int ooff,
    int ltw, float alpha,
    const float* __restrict__ add1, int a1ld, int a1off, float c1,
    const float* __restrict__ add2, int a2ld, int a2off,
    const float* __restrict__ bias, int act)
{
    const int T = 1 << ltw;
    const int lane = threadIdx.x & (T - 1);
    const int node = blockIdx.x * (256 >> ltw) + (threadIdx.x >> ltw);
    if (node >= NN) return;
    const int f4 = lane * 4;
    const int e = cnt[node];
    const int2* base = slots + (size_t)node * CAP;
    float ax = 0, ay = 0, az = 0, aw = 0;
    float bx = 0, by = 0, bz = 0, bw = 0;
    const float* zp = z + zoff + f4;
    int p = 0;
    for (; p + 4 <= e; p += 4) {
        int2 s0 = base[p + 0], s1 = base[p + 1], s2 = base[p + 2], s3 = base[p + 3];
        float w0 = __int_as_float(s0.y), w1 = __int_as_float(s1.y);
        float w2 = __int_as_float(s2.y), w3 = __int_as_float(s3.y);
        const float4 z0 = *(const float4*)(zp + (size_t)s0.x * zld);
        const float4 z1 = *(const float4*)(zp + (size_t)s1.x * zld);
        const float4 z2 = *(const float4*)(zp + (size_t)s2.x * zld);
        const float4 z3 = *(const float4*)(zp + (size_t)s3.x * zld);
        ax = fmaf(w0, z0.x, ax); ay = fmaf(w0, z0.y, ay); az = fmaf(w0, z0.z, az); aw = fmaf(w0, z0.w, aw);
        bx = fmaf(w1, z1.x, bx); by = fmaf(w1, z1.y, by); bz = fmaf(w1, z1.z, bz); bw = fmaf(w1, z1.w, bw);
        ax = fmaf(w2, z2.x, ax); ay = fmaf(w2, z2.y, ay); az = fmaf(w2, z2.z, az); aw = fmaf(w2, z2.w, aw);
        bx = fmaf(w3, z3.x, bx); by = fmaf(w3, z3.y, by); bz = fmaf(w3, z3.z, bz); bw = fmaf(w3, z3.w, bw);
    }
    for (; p < e; ++p) {
        int2 s = base[p];
        float wv = __int_as_float(s.y);
        const float4 zv = *(const float4*)(zp + (size_t)s.x * zld);
        ax = fmaf(wv, zv.x, ax); ay = fmaf(wv, zv.y, ay);
        az = fmaf(wv, zv.z, az); aw = fmaf(wv, zv.w, aw);
    }
    ax += bx; ay += by; az += bz; aw += bw;
    ax *= alpha; ay *= alpha; az *= alpha; aw *= alpha;
    if (add1) {
        const float4 t = *(const float4*)(add1 + (size_t)node * a1ld + a1off + f4);
        ax = fmaf(c1, t.x, ax); ay = fmaf(c1, t.y, ay);
        az = fmaf(c1, t.z, az); aw = fmaf(c1, t.w, aw);
    }
    if (add2) {
        const float4 t = *(const float4*)(add2 + (size_t)node * a2ld + a2off + f4);
        ax += t.x; ay += t.y; az += t.z; aw += t.w;
    }
    if (bias) {
        const float4 t = *(const float4*)(bias + f4);
        ax += t.x; ay += t.y; az += t.z; aw += t.w;
    }
    if (act) { ax = softplusf(ax); ay = softplusf(ay); az = softplusf(az); aw = softplusf(aw); }
    float4 o; o.x = ax; o.y = ay; o.z = az; o.w = aw;
    *(float4*)(out + (size_t)node * outld + ooff + f4) = o;
}

__global__ __launch_bounds__(256) void k_bnstats(const float* __restrict__ h, int ld, int lc,
                                                 float* __restrict__ stats) {
    const int C = 1 << lc;
    const int tid = threadIdx.x;
    const int c = tid & (C - 1);
    const int rpb = 256 >> lc;
    int r = blockIdx.x * rpb + (tid >> lc);
    const int stride = gridDim.x * rpb;
    float s = 0.0f, q = 0.0f;
    for (; r < NN; r += stride) {
        float v = h[r * ld + c];
        s += v;
        q = fmaf(v, v, q);
    }
    __shared__ float shs[256], shq[256];
    shs[tid] = s; shq[tid] = q;
    __syncthreads();
    for (int o = 128; o >= C; o >>= 1) {
        if (tid < o) { shs[tid] += shs[tid + o]; shq[tid] += shq[tid + o]; }
        __syncthreads();
    }
    if (tid < C) {
        atomicAdd(&stats[c], shs[tid]);
        atomicAdd(&stats[128 + c], shq[tid]);
    }
}

__global__ void k_bnapply(float* __restrict__ h, int ld, int lc,
                          const float* __restrict__ stats,
                          const float* __restrict__ g, const float* __restrict__ be) {
    int idx = blockIdx.x * 256 + threadIdx.x;
    if (idx >= (NN << lc)) return;
    int c = idx & ((1 << lc) - 1);
    int r = idx >> lc;
    const float invN = 1.0f / (float)NN;
    float m = stats[c] * invN;
    float var = fmaf(stats[128 + c], invN, -m * m);
    var = fmaxf(var, 0.0f);
    float inv = rsqrtf(var + 1e-5f);
    float v = h[r * ld + c];
    h[r * ld + c] = fmaf(g[c] * inv, v - m, be[c]);
}

static __device__ __forceinline__ int lower_bound_dev(const int* __restrict__ b, int val) {
    int lo = 0, hi = NN;
    while (lo < hi) {
        int mid = (lo + hi) >> 1;
        if (b[mid] < val) lo = mid + 1; else hi = mid;
    }
    return lo;
}

__global__ void k_gbounds(const int* __restrict__ batch, int* __restrict__ gb) {
    int g = threadIdx.x;
    if (g <= NG) gb[g] = (g == NG) ? NN : lower_bound_dev(batch, g);
}

__global__ __launch_bounds__(256) void k_pool1(const float* __restrict__ h,
                                               const int* __restrict__ gb,
                                               float* __restrict__ partial) {
    int g = blockIdx.y;
    int j = blockIdx.x;
    int start = gb[g], end = gb[g + 1];
    int len = end - start;
    int chunk = (len + 15) >> 4;
    int s = start + j * chunk;
    int e = min(s + chunk, end);
    int c = threadIdx.x;
    float mx = -INFINITY, sum = 0.0f;
    for (int r = s; r < e; ++r) {
        float v = h[(size_t)r * 256 + c];
        mx = fmaxf(mx, v);
        sum += v;
    }
    size_t base = ((size_t)(g * 16 + j)) * 512;
    partial[base + c] = mx;
    partial[base + 256 + c] = sum;
}

__global__ __launch_bounds__(256) void k_pool2(const float* __restrict__ partial,
                                               const int* __restrict__ gb,
                                               float* __restrict__ pooled) {
    int g = blockIdx.x;
    int c = threadIdx.x;
    float mx = -INFINITY, sum = 0.0f;
#pragma unroll
    for (int j = 0; j < 16; ++j) {
        size_t base = ((size_t)(g * 16 + j)) * 512;
        mx = fmaxf(mx, partial[base + c]);
        sum += partial[base + 256 + c];
    }
    int len = gb[g + 1] - gb[g];
    pooled[g * 512 + c] = (len > 0) ? mx : 0.0f;
    pooled[g * 512 + 256 + c] = sum / fmaxf((float)len, 1.0f);
}

__global__ __launch_bounds__(64) void k_dense(const float* __restrict__ pooled,
                                              const float* __restrict__ Wd,
                                              const float* __restrict__ bd,
                                              float* __restrict__ out) {
    int g = blockIdx.x;
    int t = threadIdx.x;
    float p0 = 0, p1 = 0, p2 = 0, p3 = 0;
    for (int k = t; k < 512; k += 64) {
        float pv = pooled[g * 512 + k];
        p0 = fmaf(pv, Wd[k * 4 + 0], p0);
        p1 = fmaf(pv, Wd[k * 4 + 1], p1);
        p2 = fmaf(pv, Wd[k * 4 + 2], p2);
        p3 = fmaf(pv, Wd[k * 4 + 3], p3);
    }
#pragma unroll
    for (int o = 32; o > 0; o >>= 1) {
        p0 += __shfl_down(p0, o);
        p1 += __shfl_down(p1, o);
        p2 += __shfl_down(p2, o);
        p3 += __shfl_down(p3, o);
    }
    if (t == 0) {
        float l0 = p0 + bd[0], l1 = p1 + bd[1], l2 = p2 + bd[2], l3 = p3 + bd[3];
        float m = fmaxf(fmaxf(l0, l1), fmaxf(l2, l3));
        float ls = m + logf(expf(l0 - m) + expf(l1 - m) + expf(l2 - m) + expf(l3 - m));
        out[g * 4 + 0] = l0 - ls;
        out[g * 4 + 1] = l1 - ls;
        out[g * 4 + 2] = l2 - ls;
        out[g * 4 + 3] = l3 - ls;
    }
}

extern "C" void kernel_launch(void* const* d_in, const int* in_sizes, int n_in,
                              void* d_out, int out_size, void* d_ws, size_t ws_size,
                              hipStream_t stream)
{
    const float* x    = (const float*)d_in[0];
    const float* ew   = (const float*)d_in[1];
    const int*   row  = (const int*)d_in[2];
    const int*   colp = row + NE;
    const int*   batch = (const int*)d_in[3];
    const float* W1 = (const float*)d_in[4];
    const float* b1 = (const float*)d_in[5];
    const float* g1 = (const float*)d_in[6];
    const float* be1 = (const float*)d_in[7];
    const float* W2 = (const float*)d_in[8];
    const float* b2 = (const float*)d_in[9];
    const float* g2 = (const float*)d_in[10];
    const float* be2 = (const float*)d_in[11];
    const float* W3 = (const float*)d_in[12];
    const float* b3 = (const float*)d_in[13];
    const float* g3 = (const float*)d_in[14];
    const float* be3 = (const float*)d_in[15];
    const float* W4 = (const float*)d_in[16];
    const float* b4 = (const float*)d_in[17];
    const float* g4 = (const float*)d_in[18];
    const float* be4 = (const float*)d_in[19];
    const float* W5 = (const float*)d_in[20];
    const float* b5 = (const float*)d_in[21];
    const float* Wd = (const float*)d_in[22];
    const float* bd = (const float*)d_in[23];
    float* outp = (float*)d_out;
    (void)in_sizes; (void)n_in; (void)out_size; (void)ws_size;

    char* wsb = (char*)d_ws;
    size_t off = 0;
    auto take = [&](size_t bytes) -> void* {
        void* p = wsb + off;
        off = (off + bytes + 255) & ~(size_t)255;
        return p;
    };
    int*   cnt    = (int*)take((size_t)NN * sizeof(int));
    float* deg    = (float*)take((size_t)NN * sizeof(float));
    int*   gb     = (int*)take((NG + 1) * sizeof(int));
    int2*  slots  = (int2*)take((size_t)NN * CAP * sizeof(int2));
    float* stats  = (float*)take(256 * sizeof(float));
    float* wcat   = (float*)take(6144 * sizeof(float));
    unsigned short* bt1h = (unsigned short*)take(48 * 128 * 2);
    unsigned short* bt1l = (unsigned short*)take(48 * 128 * 2);
    unsigned short* bt3h = (unsigned short*)take(64 * 96 * 2);
    unsigned short* bt3l = (unsigned short*)take(64 * 96 * 2);
    unsigned short* bt4h = (unsigned short*)take(128 * 192 * 2);
    unsigned short* bt4l = (unsigned short*)take(128 * 192 * 2);
    unsigned short* bt5h = (unsigned short*)take(256 * 384 * 2);
    unsigned short* bt5l = (unsigned short*)take(256 * 384 * 2);
    float* partial= (float*)take((size_t)NG * 16 * 512 * sizeof(float));
    float* pooled = (float*)take((size_t)NG * 512 * sizeof(float));
    float* bufA   = (float*)take((size_t)NN * 384 * sizeof(float));
    float* bufB   = (float*)take((size_t)NN * 256 * sizeof(float));

    float* P   = bufA;                        // (NN,48) layer-1 pre-transformed
    float* Hc3 = bufA;                        // (NN,96)
    float* Hc5 = bufA;                        // (NN,384)
    float* u   = bufB;                        // (NN,16)
    float* vv  = bufB + (size_t)NN * 16;      // (NN,16)
    float* Hc2 = bufB + (size_t)NN * 32;      // (NN,48)
    float* Hc4 = bufB;                        // (NN,192)
    float* h5  = bufB;                        // (NN,256)

    hipMemsetAsync(cnt, 0, NN * sizeof(int), stream);

    // ---- CSR-lite build: single atomic pass into slotted layout
    k_slot<<<6250, 256, 0, stream>>>(row, colp, ew, cnt, slots);
    k_degsum<<<3125, 256, 0, stream>>>(cnt, slots, deg);
    k_dinv<<<196, 256, 0, stream>>>(deg);
    k_rescale<<<3125, 256, 0, stream>>>(cnt, slots, deg);

    k_wcat1<<<24, 256, 0, stream>>>(W1, wcat);
    k_gbounds<<<1, 128, 0, stream>>>(batch, gb);
    k_wsplit<<<24, 256, 0, stream>>>(wcat, 128, 48, bt1h, bt1l);
    k_wsplit<<<24, 256, 0, stream>>>(W3, 96, 64, bt3h, bt3l);
    k_wsplit<<<96, 256, 0, stream>>>(W4, 192, 128, bt4h, bt4l);
    k_wsplit<<<384, 256, 0, stream>>>(W5, 384, 256, bt5h, bt5l);

    // ---- Layer 1 (128 -> 16), transformed: out = P0 + prop(P1) + 2*prop(prop(P2)) + b
    k_gemm_mfma<<<dim3(1, 391), 256, 0, stream>>>(x, 128, bt1h, bt1l, P, 48, NN, 128, 48, nullptr, 0);
    k_prop<<<782, 256, 0, stream>>>(cnt, slots, P, 48, 16, u, 16, 0, 2, 1.0f,
                                    nullptr, 0, 0, 0.0f, nullptr, 0, 0, nullptr, 0);
    k_prop<<<782, 256, 0, stream>>>(cnt, slots, P, 48, 32, vv, 16, 0, 2, 1.0f,
                                    nullptr, 0, 0, 0.0f, nullptr, 0, 0, nullptr, 0);
    k_prop<<<782, 256, 0, stream>>>(cnt, slots, vv, 16, 0, Hc2, 48, 0, 2, 2.0f,
                                    P, 48, 0, 1.0f, u, 16, 0, b1, 1);
    hipMemsetAsync(stats, 0, 1024, stream);
    k_bnstats<<<256, 256, 0, stream>>>(Hc2, 48, 4, stats);
    k_bnapply<<<(NN * 16 + 255) / 256, 256, 0, stream>>>(Hc2, 48, 4, stats, g1, be1);

    // ---- Layer 2 (16 -> 32)
    k_prop<<<782, 256, 0, stream>>>(cnt, slots, Hc2, 48, 0, Hc2, 48, 16, 2, 1.0f,
                                    nullptr, 0, 0, 0.0f, nullptr, 0, 0, nullptr, 0);
    k_prop<<<782, 256, 0, stream>>>(cnt, slots, Hc2, 48, 16, Hc2, 48, 32, 2, 2.0f,
                                    Hc2, 48, 0, -1.0f, nullptr, 0, 0, nullptr, 0);
    k_gemm<<<dim3(1, 391), 256, 0, stream>>>(Hc2, 48, W2, 32, Hc3, 96, NN, 48, 32, b2, 1);
    hipMemsetAsync(stats, 0, 1024, stream);
    k_bnstats<<<256, 256, 0, stream>>>(Hc3, 96, 5, stats);
    k_bnapply<<<(NN * 32 + 255) / 256, 256, 0, stream>>>(Hc3, 96, 5, stats, g2, be2);

    // ---- Layer 3 (32 -> 64)
    k_prop<<<1563, 256, 0, stream>>>(cnt, slots, Hc3, 96, 0, Hc3, 96, 32, 3, 1.0f,
                                     nullptr, 0, 0, 0.0f, nullptr, 0, 0, nullptr, 0);
    k_prop<<<1563, 256, 0, stream>>>(cnt, slots, Hc3, 96, 32, Hc3, 96, 64, 3, 2.0f,
                                     Hc3, 96, 0, -1.0f, nullptr, 0, 0, nullptr, 0);
    k_gemm_mfma<<<dim3(1, 391), 256, 0, stream>>>(Hc3, 96, bt3h, bt3l, Hc4, 192, NN, 96, 64, b3, 1);
    hipMemsetAsync(stats, 0, 1024, stream);
    k_bnstats<<<256, 256, 0, stream>>>(Hc4, 192, 6, stats);
    k_bnapply<<<(NN * 64 + 255) / 256, 256, 0, stream>>>(Hc4, 192, 6, stats, g3, be3);

    // ---- Layer 4 (64 -> 128)
    k_prop<<<3125, 256, 0, stream>>>(cnt, slots, Hc4, 192, 0, Hc4, 192, 64, 4, 1.0f,
                                     nullptr, 0, 0, 0.0f, nullptr, 0, 0, nullptr, 0);
    k_prop<<<3125, 256, 0, stream>>>(cnt, slots, Hc4, 192, 64, Hc4, 192, 128, 4, 2.0f,
                                     Hc4, 192, 0, -1.0f, nullptr, 0, 0, nullptr, 0);
    k_gemm_mfma<<<dim3(1, 391), 256, 0, stream>>>(Hc4, 192, bt4h, bt4l, Hc5, 384, NN, 192, 128, b4, 1);
    hipMemsetAsync(stats, 0, 1024, stream);
    k_bnstats<<<256, 256, 0, stream>>>(Hc5, 384, 7, stats);
    k_bnapply<<<(NN * 128 + 255) / 256, 256, 0, stream>>>(Hc5, 384, 7, stats, g4, be4);

    // ---- Layer 5 (128 -> 256), no BN/act
    k_prop<<<6250, 256, 0, stream>>>(cnt, slots, Hc5, 384, 0, Hc5, 384, 128, 5, 1.0f,
                                     nullptr, 0, 0, 0.0f, nullptr, 0, 0, nullptr, 0);
    k_prop<<<6250, 256, 0, stream>>>(cnt, slots, Hc5, 384, 128, Hc5, 384, 256, 5, 2.0f,
                                     Hc5, 384, 0, -1.0f, nullptr, 0, 0, nullptr, 0);
    k_gemm_mfma<<<dim3(2, 391), 256, 0, stream>>>(Hc5, 384, bt5h, bt5l, h5, 256, NN, 384, 256, b5, 0);

    // ---- Pool + dense + log_softmax
    k_pool1<<<dim3(16, 64), 256, 0, stream>>>(h5, gb, partial);
    k_pool2<<<64, 256, 0, stream>>>(partial, gb, pooled);
    k_dense<<<64, 64, 0, stream>>>(pooled, Wd, bd, outp);
}

// Round 5
// 874.345 us; speedup vs baseline: 1.9431x; 1.4059x over previous
//
#include <hip/hip_runtime.h>
#include <cmath>

#define NN 50000
#define NE 1600000
#define NG 64
#define CAP 96   // slots per row; deg ~ Poisson(32), P(deg>=96) ~ e^-41 -> safe

typedef __attribute__((ext_vector_type(8))) short short8_t;
typedef __attribute__((ext_vector_type(4))) float floatx4;
typedef __attribute__((ext_vector_type(4))) unsigned short us4;

static __device__ __forceinline__ float softplusf(float x) {
    return fmaxf(x, 0.0f) + log1pf(expf(-fabsf(x)));
}

static __device__ __forceinline__ float bf2f(unsigned short u) {
    return __uint_as_float(((unsigned)u) << 16);
}
static __device__ __forceinline__ unsigned short f2bf(float x) {
    unsigned u = __float_as_uint(x);
    unsigned t = (u >> 16) & 1u;
    return (unsigned short)((u + 0x7FFFu + t) >> 16);  // RNE
}

// exact split x = hi + lo (bf16 each, ~2^-16 relative residual)
static __device__ __forceinline__ void split_bf16(float x, unsigned short& hi, unsigned short& lo) {
    unsigned u = __float_as_uint(x);
    unsigned hb = u & 0xFFFF0000u;
    hi = (unsigned short)(hb >> 16);
    float r = x - __uint_as_float(hb);   // exact
    lo = f2bf(r);
}

// Single-pass slotted CSR build: 1 atomic + one 8B store per edge.
__global__ void k_slot(const int* __restrict__ row, const int* __restrict__ col,
                       const float* __restrict__ w,
                       int* __restrict__ cnt, int2* __restrict__ slots) {
    int e = blockIdx.x * blockDim.x + threadIdx.x;
    if (e < NE) {
        int r = row[e];
        int k = atomicAdd(&cnt[r], 1);
        k = min(k, CAP - 1);  // defensive
        slots[(size_t)r * CAP + k] = make_int2(col[e], __float_as_int(w[e]));
    }
}

// dinv[r] = rsqrt(sum of raw w over row r), 0 if deg<=0 (atomic-free)
__global__ __launch_bounds__(256) void k_degsum(const int* __restrict__ cnt,
                                                const int2* __restrict__ slots,
                                                float* __restrict__ dinv) {
    int tid = threadIdx.x;
    int lane = tid & 15;
    int node = blockIdx.x * 16 + (tid >> 4);
    if (node >= NN) return;
    int e = cnt[node];
    const int2* base = slots + (size_t)node * CAP;
    float s = 0.0f;
    for (int k = lane; k < e; k += 16) s += __int_as_float(base[k].y);
#pragma unroll
    for (int m = 8; m >= 1; m >>= 1) s += __shfl_xor(s, m);
    if (lane == 0) dinv[node] = (s > 0.0f) ? rsqrtf(s) : 0.0f;
}

// In-place: slot.y = -w * dinv[r] * dinv[col]
__global__ __launch_bounds__(256) void k_rescale(const int* __restrict__ cnt,
                                                 int2* __restrict__ slots,
                                                 const float* __restrict__ dinv) {
    int tid = threadIdx.x;
    int lane = tid & 15;
    int node = blockIdx.x * 16 + (tid >> 4);
    if (node >= NN) return;
    int e = cnt[node];
    float dr = dinv[node];
    int2* base = slots + (size_t)node * CAP;
    for (int k = lane; k < e; k += 16) {
        int2 s = base[k];
        float wv = __int_as_float(s.y);
        base[k].y = __float_as_int(-wv * dr * dinv[s.x]);
    }
}

// Wcat1 (128 x 48) = [W0-W2 | W1 | W2] from W1 input (3,128,16)
__global__ void k_wcat1(const float* __restrict__ W1, float* __restrict__ wc) {
    int i = blockIdx.x * blockDim.x + threadIdx.x;
    if (i < 128 * 48) {
        int k = i / 48, j = i - k * 48;
        float v;
        if (j < 16)      v = W1[k * 16 + j] - W1[2 * 2048 + k * 16 + j];
        else if (j < 32) v = W1[2048 + k * 16 + (j - 16)];
        else             v = W1[2 * 2048 + k * 16 + (j - 32)];
        wc[i] = v;
    }
}

// Split W (K,N) fp32 into transposed hi/lo bf16: hiT/loT are (N,K)
__global__ void k_wsplit(const float* __restrict__ W, int K, int N,
                         unsigned short* __restrict__ hiT, unsigned short* __restrict__ loT) {
    int idx = blockIdx.x * 256 + threadIdx.x;
    if (idx < K * N) {
        int k = idx / N, n = idx - k * N;
        unsigned short h, l;
        split_bf16(W[idx], h, l);
        hiT[(size_t)n * K + k] = h;
        loT[(size_t)n * K + k] = l;
    }
}

#define ASTR 40  // padded LDS row stride in ushorts (32 + 8)

// ---------------- MFMA GEMM, fp32 A (3-term split), bf16 C. Layer 1 only.
__global__ __launch_bounds__(256, 2) void k_gemm_mfma_f32A(
    const float* __restrict__ A, int lda,
    const unsigned short* __restrict__ BhiT,
    const unsigned short* __restrict__ BloT,
    unsigned short* __restrict__ C, int ldc,
    int M, int K, int Ncol)
{
    __shared__ unsigned short Ah[128 * ASTR];
    __shared__ unsigned short Al[128 * ASTR];
    __shared__ unsigned short Bh[128 * ASTR];
    __shared__ unsigned short Bl[128 * ASTR];

    const int tid = threadIdx.x;
    const int lane = tid & 63;
    const int wave = tid >> 6;
    const int wm = wave >> 1, wn = wave & 1;
    const int quad = lane >> 4, l16 = lane & 15;
    const int bm = blockIdx.y * 128, bn = blockIdx.x * 128;
    const int srow = tid >> 1;
    const int skq  = (tid & 1) * 16;

    floatx4 acc[4][4];
#pragma unroll
    for (int i = 0; i < 4; ++i)
#pragma unroll
        for (int j = 0; j < 4; ++j) acc[i][j] = (floatx4){0.f, 0.f, 0.f, 0.f};

    for (int k0 = 0; k0 < K; k0 += 32) {
        float4 a0 = make_float4(0, 0, 0, 0), a1 = a0, a2 = a0, a3 = a0;
        const int ga = bm + srow;
        if (ga < M) {
            const float* Ap = A + (size_t)ga * lda + k0 + skq;
            a0 = *(const float4*)(Ap + 0);
            a1 = *(const float4*)(Ap + 4);
            a2 = *(const float4*)(Ap + 8);
            a3 = *(const float4*)(Ap + 12);
        }
        uint4 bh0 = make_uint4(0, 0, 0, 0), bh1 = bh0, bl0 = bh0, bl1 = bh0;
        const int gb = bn + srow;
        if (gb < Ncol) {
            const unsigned short* ph = BhiT + (size_t)gb * K + k0 + skq;
            const unsigned short* pl = BloT + (size_t)gb * K + k0 + skq;
            bh0 = *(const uint4*)(ph);
            bh1 = *(const uint4*)(ph + 8);
            bl0 = *(const uint4*)(pl);
            bl1 = *(const uint4*)(pl + 8);
        }
        __attribute__((aligned(16))) unsigned short ah[16], al[16];
        const float av[16] = {a0.x, a0.y, a0.z, a0.w, a1.x, a1.y, a1.z, a1.w,
                              a2.x, a2.y, a2.z, a2.w, a3.x, a3.y, a3.z, a3.w};
#pragma unroll
        for (int i = 0; i < 16; ++i) split_bf16(av[i], ah[i], al[i]);

        __syncthreads();
        *(uint4*)&Ah[srow * ASTR + skq]     = *(const uint4*)&ah[0];
        *(uint4*)&Ah[srow * ASTR + skq + 8] = *(const uint4*)&ah[8];
        *(uint4*)&Al[srow * ASTR + skq]     = *(const uint4*)&al[0];
        *(uint4*)&Al[srow * ASTR + skq + 8] = *(const uint4*)&al[8];
        *(uint4*)&Bh[srow * ASTR + skq]     = bh0;
        *(uint4*)&Bh[srow * ASTR + skq + 8] = bh1;
        *(uint4*)&Bl[srow * ASTR + skq]     = bl0;
        *(uint4*)&Bl[srow * ASTR + skq + 8] = bl1;
        __syncthreads();

        short8_t afh[4], afl[4], bfh[4], bfl[4];
#pragma unroll
        for (int t = 0; t < 4; ++t) {
            const int m = wm * 64 + t * 16 + l16;
            afh[t] = *(const short8_t*)&Ah[m * ASTR + quad * 8];
            afl[t] = *(const short8_t*)&Al[m * ASTR + quad * 8];
            const int n = wn * 64 + t * 16 + l16;
            bfh[t] = *(const short8_t*)&Bh[n * ASTR + quad * 8];
            bfl[t] = *(const short8_t*)&Bl[n * ASTR + quad * 8];
        }
#pragma unroll
        for (int i = 0; i < 4; ++i)
#pragma unroll
            for (int j = 0; j < 4; ++j) {
                acc[i][j] = __builtin_amdgcn_mfma_f32_16x16x32_bf16(afh[i], bfh[j], acc[i][j], 0, 0, 0);
                acc[i][j] = __builtin_amdgcn_mfma_f32_16x16x32_bf16(afh[i], bfl[j], acc[i][j], 0, 0, 0);
                acc[i][j] = __builtin_amdgcn_mfma_f32_16x16x32_bf16(afl[i], bfh[j], acc[i][j], 0, 0, 0);
            }
    }

#pragma unroll
    for (int j = 0; j < 4; ++j) {
        const int col = bn + wn * 64 + j * 16 + l16;
        if (col >= Ncol) continue;
#pragma unroll
        for (int i = 0; i < 4; ++i) {
#pragma unroll
            for (int r = 0; r < 4; ++r) {
                const int row = bm + wm * 64 + i * 16 + quad * 4 + r;
                if (row >= M) continue;
                C[(size_t)row * ldc + col] = f2bf(acc[i][j][r]);
            }
        }
    }
}

// ---------------- MFMA GEMM, bf16 A direct (2-term W split). Layers 3/4/5.
__global__ __launch_bounds__(256, 2) void k_gemm_mfma_bf(
    const unsigned short* __restrict__ A, int lda,
    const unsigned short* __restrict__ BhiT,
    const unsigned short* __restrict__ BloT,
    void* __restrict__ Cv, int ldc,
    int M, int K, int Ncol,
    const float* __restrict__ bias, int act, int c_f32)
{
    __shared__ unsigned short Ah[128 * ASTR];
    __shared__ unsigned short Bh[128 * ASTR];
    __shared__ unsigned short Bl[128 * ASTR];

    const int tid = threadIdx.x;
    const int lane = tid & 63;
    const int wave = tid >> 6;
    const int wm = wave >> 1, wn = wave & 1;
    const int quad = lane >> 4, l16 = lane & 15;
    const int bm = blockIdx.y * 128, bn = blockIdx.x * 128;
    const int srow = tid >> 1;
    const int skq  = (tid & 1) * 16;

    floatx4 acc[4][4];
#pragma unroll
    for (int i = 0; i < 4; ++i)
#pragma unroll
        for (int j = 0; j < 4; ++j) acc[i][j] = (floatx4){0.f, 0.f, 0.f, 0.f};

    for (int k0 = 0; k0 < K; k0 += 32) {
        uint4 a0 = make_uint4(0, 0, 0, 0), a1 = a0;
        const int ga = bm + srow;
        if (ga < M) {
            const unsigned short* Ap = A + (size_t)ga * lda + k0 + skq;
            a0 = *(const uint4*)(Ap);
            a1 = *(const uint4*)(Ap + 8);
        }
        uint4 bh0 = make_uint4(0, 0, 0, 0), bh1 = bh0, bl0 = bh0, bl1 = bh0;
        const int gb = bn + srow;
        if (gb < Ncol) {
            const unsigned short* ph = BhiT + (size_t)gb * K + k0 + skq;
            const unsigned short* pl = BloT + (size_t)gb * K + k0 + skq;
            bh0 = *(const uint4*)(ph);
            bh1 = *(const uint4*)(ph + 8);
            bl0 = *(const uint4*)(pl);
            bl1 = *(const uint4*)(pl + 8);
        }
        __syncthreads();
        *(uint4*)&Ah[srow * ASTR + skq]     = a0;
        *(uint4*)&Ah[srow * ASTR + skq + 8] = a1;
        *(uint4*)&Bh[srow * ASTR + skq]     = bh0;
        *(uint4*)&Bh[srow * ASTR + skq + 8] = bh1;
        *(uint4*)&Bl[srow * ASTR + skq]     = bl0;
        *(uint4*)&Bl[srow * ASTR + skq + 8] = bl1;
        __syncthreads();

        short8_t afh[4], bfh[4], bfl[4];
#pragma unroll
        for (int t = 0; t < 4; ++t) {
            const int m = wm * 64 + t * 16 + l16;
            afh[t] = *(const short8_t*)&Ah[m * ASTR + quad * 8];
            const int n = wn * 64 + t * 16 + l16;
            bfh[t] = *(const short8_t*)&Bh[n * ASTR + quad * 8];
            bfl[t] = *(const short8_t*)&Bl[n * ASTR + quad * 8];
        }
#pragma unroll
        for (int i = 0; i < 4; ++i)
#pragma unroll
            for (int j = 0; j < 4; ++j) {
                acc[i][j] = __builtin_amdgcn_mfma_f32_16x16x32_bf16(afh[i], bfh[j], acc[i][j], 0, 0, 0);
                acc[i][j] = __builtin_amdgcn_mfma_f32_16x16x32_bf16(afh[i], bfl[j], acc[i][j], 0, 0, 0);
            }
    }

    float* Cf = (float*)Cv;
    unsigned short* Cb = (unsigned short*)Cv;
#pragma unroll
    for (int j = 0; j < 4; ++j) {
        const int col = bn + wn * 64 + j * 16 + l16;
        if (col >= Ncol) continue;
        const float bv = bias ? bias[col] : 0.0f;
#pragma unroll
        for (int i = 0; i < 4; ++i) {
#pragma unroll
            for (int r = 0; r < 4; ++r) {
                const int row = bm + wm * 64 + i * 16 + quad * 4 + r;
                if (row >= M) continue;
                float v = acc[i][j][r] + bv;
                if (act) v = softplusf(v);
                if (c_f32) Cf[(size_t)row * ldc + col] = v;
                else       Cb[(size_t)row * ldc + col] = f2bf(v);
            }
        }
    }
}

// fp32-weight vector GEMM with bf16 A and bf16 C (layer 2 only, K=48)
__global__ __launch_bounds__(256) void k_gemm(
    const unsigned short* __restrict__ A, int lda,
    const float* __restrict__ B, int ldb,
    unsigned short* __restrict__ C, int ldc,
    int M, int K, int Ncol,
    const float* __restrict__ bias, int act)
{
    __shared__ float As[16][128];
    __shared__ float Bs[16][128];
    const int tid = threadIdx.x;
    const int tx = tid & 15;
    const int ty = tid >> 4;
    const int bm = blockIdx.y * 128;
    const int bn = blockIdx.x * 128;
    const int arow = tid >> 1;
    const int akq = (tid & 1) * 8;
    const int bkr = tid >> 4;
    const int bcq = (tid & 15) * 8;

    float acc[8][8];
#pragma unroll
    for (int i = 0; i < 8; ++i)
#pragma unroll
        for (int j = 0; j < 8; ++j) acc[i][j] = 0.0f;

    for (int k0 = 0; k0 < K; k0 += 16) {
        uint4 ald = make_uint4(0, 0, 0, 0);
        int gr = bm + arow;
        if (gr < M) ald = *(const uint4*)(A + (size_t)gr * lda + k0 + akq);
        float4 b0 = make_float4(0, 0, 0, 0), b1 = make_float4(0, 0, 0, 0);
        int cb = bn + bcq;
        const float* Bp = B + (k0 + bkr) * ldb;
        if (cb < Ncol)     b0 = *(const float4*)(Bp + cb);
        if (cb + 4 < Ncol) b1 = *(const float4*)(Bp + cb + 4);
        __syncthreads();
        const unsigned short* au = (const unsigned short*)&ald;
#pragma unroll
        for (int i = 0; i < 8; ++i) As[akq + i][arow] = bf2f(au[i]);
        *(float4*)&Bs[bkr][bcq] = b0;
        *(float4*)&Bs[bkr][bcq + 4] = b1;
        __syncthreads();
#pragma unroll
        for (int kk = 0; kk < 16; ++kk) {
            float a[8], b[8];
            float4 t;
            t = *(const float4*)&As[kk][ty * 4];      a[0] = t.x; a[1] = t.y; a[2] = t.z; a[3] = t.w;
            t = *(const float4*)&As[kk][64 + ty * 4]; a[4] = t.x; a[5] = t.y; a[6] = t.z; a[7] = t.w;
            t = *(const float4*)&Bs[kk][tx * 4];      b[0] = t.x; b[1] = t.y; b[2] = t.z; b[3] = t.w;
            t = *(const float4*)&Bs[kk][64 + tx * 4]; b[4] = t.x; b[5] = t.y; b[6] = t.z; b[7] = t.w;
#pragma unroll
            for (int i = 0; i < 8; ++i)
#pragma unroll
                for (int j = 0; j < 8; ++j)
                    acc[i][j] = fmaf(a[i], b[j], acc[i][j]);
        }
    }
#pragma unroll
    for (int i = 0; i < 8; ++i) {
        int r = bm + ((i < 4) ? (ty * 4 + i) : (64 + ty * 4 + i - 4));
        if (r >= M) continue;
#pragma unroll
        for (int j = 0; j < 8; ++j) {
            int cl = bn + ((j < 4) ? (tx * 4 + j) : (64 + tx * 4 + j - 4));
            if (cl >= Ncol) continue;
            float v = acc[i][j];
            if (bias) v += bias[cl];
            if (act) v = softplusf(v);
            C[(size_t)r * ldc + cl] = f2bf(v);
        }
    }
}

// Slotted propagation over bf16 activations (fp32 accumulate, bf16 out).
__global__ __launch_bounds__(256) void k_prop(
    const int* __restrict__ cnt, const int2* __restrict__ slots,
    const unsigned short* __restrict__ z, int zld, int zoff,
    unsigned short* __restrict__ out, int outld, int ooff,
    int ltw, float alpha,
    const unsigned short* __restrict__ add1, int a1ld, int a1off, float c1,
    const unsigned short* __restrict__ add2, int a2ld, int a2off,
    const float* __restrict__ bias, int act)
{
    const int T = 1 << ltw;
    const int lane = threadIdx.x & (T - 1);
    const int node = blockIdx.x * (256 >> ltw) + (threadIdx.x >> ltw);
    if (node >= NN) return;
    const int f4 = lane * 4;
    const int e = cnt[node];
    const int2* base = slots + (size_t)node * CAP;
    float ax = 0, ay = 0, az = 0, aw = 0;
    float bx = 0, by = 0, bz = 0, bw = 0;
    const unsigned short* zp = z + zoff + f4;
    int p = 0;
    for (; p + 4 <= e; p += 4) {
        int2 s0 = base[p + 0], s1 = base[p + 1], s2 = base[p + 2], s3 = base[p + 3];
        float w0 = __int_as_float(s0.y), w1 = __int_as_float(s1.y);
        float w2 = __int_as_float(s2.y), w3 = __int_as_float(s3.y);
        const us4 z0 = *(const us4*)(zp + (size_t)s0.x * zld);
        const us4 z1 = *(const us4*)(zp + (size_t)s1.x * zld);
        const us4 z2 = *(const us4*)(zp + (size_t)s2.x * zld);
        const us4 z3 = *(const us4*)(zp + (size_t)s3.x * zld);
        ax = fmaf(w0, bf2f(z0.x), ax); ay = fmaf(w0, bf2f(z0.y), ay);
        az = fmaf(w0, bf2f(z0.z), az); aw = fmaf(w0, bf2f(z0.w), aw);
        bx = fmaf(w1, bf2f(z1.x), bx); by = fmaf(w1, bf2f(z1.y), by);
        bz = fmaf(w1, bf2f(z1.z), bz); bw = fmaf(w1, bf2f(z1.w), bw);
        ax = fmaf(w2, bf2f(z2.x), ax); ay = fmaf(w2, bf2f(z2.y), ay);
        az = fmaf(w2, bf2f(z2.z), az); aw = fmaf(w2, bf2f(z2.w), aw);
        bx = fmaf(w3, bf2f(z3.x), bx); by = fmaf(w3, bf2f(z3.y), by);
        bz = fmaf(w3, bf2f(z3.z), bz); bw = fmaf(w3, bf2f(z3.w), bw);
    }
    for (; p < e; ++p) {
        int2 s = base[p];
        float wv = __int_as_float(s.y);
        const us4 zv = *(const us4*)(zp + (size_t)s.x * zld);
        ax = fmaf(wv, bf2f(zv.x), ax); ay = fmaf(wv, bf2f(zv.y), ay);
        az = fmaf(wv, bf2f(zv.z), az); aw = fmaf(wv, bf2f(zv.w), aw);
    }
    ax += bx; ay += by; az += bz; aw += bw;
    ax *= alpha; ay *= alpha; az *= alpha; aw *= alpha;
    if (add1) {
        const us4 t = *(const us4*)(add1 + (size_t)node * a1ld + a1off + f4);
        ax = fmaf(c1, bf2f(t.x), ax); ay = fmaf(c1, bf2f(t.y), ay);
        az = fmaf(c1, bf2f(t.z), az); aw = fmaf(c1, bf2f(t.w), aw);
    }
    if (add2) {
        const us4 t = *(const us4*)(add2 + (size_t)node * a2ld + a2off + f4);
        ax += bf2f(t.x); ay += bf2f(t.y); az += bf2f(t.z); aw += bf2f(t.w);
    }
    if (bias) {
        const float4 t = *(const float4*)(bias + f4);
        ax += t.x; ay += t.y; az += t.z; aw += t.w;
    }
    if (act) { ax = softplusf(ax); ay = softplusf(ay); az = softplusf(az); aw = softplusf(aw); }
    us4 o;
    o.x = f2bf(ax); o.y = f2bf(ay); o.z = f2bf(az); o.w = f2bf(aw);
    *(us4*)(out + (size_t)node * outld + ooff + f4) = o;
}

__global__ __launch_bounds__(256) void k_bnstats(const unsigned short* __restrict__ h, int ld, int lc,
                                                 float* __restrict__ stats) {
    const int C = 1 << lc;
    const int tid = threadIdx.x;
    const int c = tid & (C - 1);
    const int rpb = 256 >> lc;
    int r = blockIdx.x * rpb + (tid >> lc);
    const int stride = gridDim.x * rpb;
    float s = 0.0f, q = 0.0f;
    for (; r < NN; r += stride) {
        float v = bf2f(h[(size_t)r * ld + c]);
        s += v;
        q = fmaf(v, v, q);
    }
    __shared__ float shs[256], shq[256];
    shs[tid] = s; shq[tid] = q;
    __syncthreads();
    for (int o = 128; o >= C; o >>= 1) {
        if (tid < o) { shs[tid] += shs[tid + o]; shq[tid] += shq[tid + o]; }
        __syncthreads();
    }
    if (tid < C) {
        atomicAdd(&stats[c], shs[tid]);
        atomicAdd(&stats[128 + c], shq[tid]);
    }
}

__global__ void k_bnapply(unsigned short* __restrict__ h, int ld, int lc,
                          const float* __restrict__ stats,
                          const float* __restrict__ g, const float* __restrict__ be) {
    int idx = blockIdx.x * 256 + threadIdx.x;
    if (idx >= (NN << lc)) return;
    int c = idx & ((1 << lc) - 1);
    int r = idx >> lc;
    const float invN = 1.0f / (float)NN;
    float m = stats[c] * invN;
    float var = fmaf(stats[128 + c], invN, -m * m);
    var = fmaxf(var, 0.0f);
    float inv = rsqrtf(var + 1e-5f);
    float v = bf2f(h[(size_t)r * ld + c]);
    h[(size_t)r * ld + c] = f2bf(fmaf(g[c] * inv, v - m, be[c]));
}

static __device__ __forceinline__ int lower_bound_dev(const int* __restrict__ b, int val) {
    int lo = 0, hi = NN;
    while (lo < hi) {
        int mid = (lo + hi) >> 1;
        if (b[mid] < val) lo = mid + 1; else hi = mid;
    }
    return lo;
}

__global__ void k_gbounds(const int* __restrict__ batch, int* __restrict__ gb) {
    int g = threadIdx.x;
    if (g <= NG) gb[g] = (g == NG) ? NN : lower_bound_dev(batch, g);
}

__global__ __launch_bounds__(256) void k_pool1(const float* __restrict__ h,
                                               const int* __restrict__ gb,
                                               float* __restrict__ partial) {
    int g = blockIdx.y;
    int j = blockIdx.x;
    int start = gb[g], end = gb[g + 1];
    int len = end - start;
    int chunk = (len + 15) >> 4;
    int s = start + j * chunk;
    int e = min(s + chunk, end);
    int c = threadIdx.x;
    float mx = -INFINITY, sum = 0.0f;
    for (int r = s; r < e; ++r) {
        float v = h[(size_t)r * 256 + c];
        mx = fmaxf(mx, v);
        sum += v;
    }
    size_t base = ((size_t)(g * 16 + j)) * 512;
    partial[base + c] = mx;
    partial[base + 256 + c] = sum;
}

// Fused pool stage 2 + dense + log_softmax: 64 blocks.
__global__ __launch_bounds__(256) void k_pool2d(const float* __restrict__ partial,
                                                const int* __restrict__ gb,
                                                const float* __restrict__ Wd,
                                                const float* __restrict__ bd,
                                                float* __restrict__ out) {
    __shared__ float pl[512];
    __shared__ float red[4][256];
    int g = blockIdx.x;
    int c = threadIdx.x;
    float mx = -INFINITY, sum = 0.0f;
#pragma unroll
    for (int j = 0; j < 16; ++j) {
        size_t base = ((size_t)(g * 16 + j)) * 512;
        mx = fmaxf(mx, partial[base + c]);
        sum += partial[base + 256 + c];
    }
    int len = gb[g + 1] - gb[g];
    pl[c] = (len > 0) ? mx : 0.0f;
    pl[256 + c] = sum / fmaxf((float)len, 1.0f);
    __syncthreads();
    float p[4] = {0, 0, 0, 0};
    for (int k = c; k < 512; k += 256) {
        float pv = pl[k];
#pragma unroll
        for (int cc = 0; cc < 4; ++cc) p[cc] = fmaf(pv, Wd[k * 4 + cc], p[cc]);
    }
#pragma unroll
    for (int cc = 0; cc < 4; ++cc) red[cc][c] = p[cc];
    __syncthreads();
    for (int o = 128; o >= 1; o >>= 1) {
        if (c < o) {
#pragma unroll
            for (int cc = 0; cc < 4; ++cc) red[cc][c] += red[cc][c + o];
        }
        __syncthreads();
    }
    if (c == 0) {
        float l0 = red[0][0] + bd[0], l1 = red[1][0] + bd[1];
        float l2 = red[2][0] + bd[2], l3 = red[3][0] + bd[3];
        float m = fmaxf(fmaxf(l0, l1), fmaxf(l2, l3));
        float ls = m + logf(expf(l0 - m) + expf(l1 - m) + expf(l2 - m) + expf(l3 - m));
        out[g * 4 + 0] = l0 - ls;
        out[g * 4 + 1] = l1 - ls;
        out[g * 4 + 2] = l2 - ls;
        out[g * 4 + 3] = l3 - ls;
    }
}

extern "C" void kernel_launch(void* const* d_in, const int* in_sizes, int n_in,
                              void* d_out, int out_size, void* d_ws, size_t ws_size,
                              hipStream_t stream)
{
    const float* x    = (const float*)d_in[0];
    const float* ew   = (const float*)d_in[1];
    const int*   row  = (const int*)d_in[2];
    const int*   colp = row + NE;
    const int*   batch = (const int*)d_in[3];
    const float* W1 = (const float*)d_in[4];
    const float* b1 = (const float*)d_in[5];
    const float* g1 = (const float*)d_in[6];
    const float* be1 = (const float*)d_in[7];
    const float* W2 = (const float*)d_in[8];
    const float* b2 = (const float*)d_in[9];
    const float* g2 = (const float*)d_in[10];
    const float* be2 = (const float*)d_in[11];
    const float* W3 = (const float*)d_in[12];
    const float* b3 = (const float*)d_in[13];
    const float* g3 = (const float*)d_in[14];
    const float* be3 = (const float*)d_in[15];
    const float* W4 = (const float*)d_in[16];
    const float* b4 = (const float*)d_in[17];
    const float* g4 = (const float*)d_in[18];
    const float* be4 = (const float*)d_in[19];
    const float* W5 = (const float*)d_in[20];
    const float* b5 = (const float*)d_in[21];
    const float* Wd = (const float*)d_in[22];
    const float* bd = (const float*)d_in[23];
    float* outp = (float*)d_out;
    (void)in_sizes; (void)n_in; (void)out_size; (void)ws_size; (void)ew;

    char* wsb = (char*)d_ws;
    size_t off = 0;
    auto take = [&](size_t bytes) -> void* {
        void* p = wsb + off;
        off = (off + bytes + 255) & ~(size_t)255;
        return p;
    };
    int*   cnt    = (int*)take((size_t)NN * sizeof(int));
    float* dinv   = (float*)take((size_t)NN * sizeof(float));
    int*   gb     = (int*)take((NG + 1) * sizeof(int));
    int2*  slots  = (int2*)take((size_t)NN * CAP * sizeof(int2));
    float* statsA = (float*)take(4 * 256 * sizeof(float));
    float* wcat   = (float*)take(6144 * sizeof(float));
    unsigned short* bt1h = (unsigned short*)take(48 * 128 * 2);
    unsigned short* bt1l = (unsigned short*)take(48 * 128 * 2);
    unsigned short* bt3h = (unsigned short*)take(64 * 96 * 2);
    unsigned short* bt3l = (unsigned short*)take(64 * 96 * 2);
    unsigned short* bt4h = (unsigned short*)take(128 * 192 * 2);
    unsigned short* bt4l = (unsigned short*)take(128 * 192 * 2);
    unsigned short* bt5h = (unsigned short*)take(256 * 384 * 2);
    unsigned short* bt5l = (unsigned short*)take(256 * 384 * 2);
    float* partial= (float*)take((size_t)NG * 16 * 512 * sizeof(float));
    unsigned short* P   = (unsigned short*)take((size_t)NN * 48 * 2);
    unsigned short* uv  = (unsigned short*)take((size_t)NN * 32 * 2);
    unsigned short* Hc2 = (unsigned short*)take((size_t)NN * 48 * 2);
    unsigned short* Hc3 = (unsigned short*)take((size_t)NN * 96 * 2);
    unsigned short* Hc4 = (unsigned short*)take((size_t)NN * 192 * 2);
    unsigned short* Hc5 = (unsigned short*)take((size_t)NN * 384 * 2);
    float* h5   = (float*)take((size_t)NN * 256 * sizeof(float));

    float* stats1 = statsA;
    float* stats2 = statsA + 256;
    float* stats3 = statsA + 512;
    float* stats4 = statsA + 768;

    hipMemsetAsync(cnt, 0, NN * sizeof(int), stream);
    hipMemsetAsync(statsA, 0, 4 * 256 * sizeof(float), stream);

    // ---- adjacency build
    k_slot<<<6250, 256, 0, stream>>>(row, colp, ew, cnt, slots);
    k_degsum<<<3125, 256, 0, stream>>>(cnt, slots, dinv);
    k_rescale<<<3125, 256, 0, stream>>>(cnt, slots, dinv);

    // ---- weight prep
    k_wcat1<<<24, 256, 0, stream>>>(W1, wcat);
    k_gbounds<<<1, 128, 0, stream>>>(batch, gb);
    k_wsplit<<<24, 256, 0, stream>>>(wcat, 128, 48, bt1h, bt1l);
    k_wsplit<<<24, 256, 0, stream>>>(W3, 96, 64, bt3h, bt3l);
    k_wsplit<<<96, 256, 0, stream>>>(W4, 192, 128, bt4h, bt4l);
    k_wsplit<<<384, 256, 0, stream>>>(W5, 384, 256, bt5h, bt5l);

    // ---- Layer 1 (128->16): P = x @ [W0-W2 | W1 | W2];  h1 = P0 + prop(P1) + 2*prop(prop(P2)) + b
    k_gemm_mfma_f32A<<<dim3(1, 391), 256, 0, stream>>>(x, 128, bt1h, bt1l, P, 48, NN, 128, 48);
    // fused: uv[:,0:16]=prop(P1), uv[:,16:32]=prop(P2)  (one width-32 gather)
    k_prop<<<1563, 256, 0, stream>>>(cnt, slots, P, 48, 16, uv, 32, 0, 3, 1.0f,
                                     nullptr, 0, 0, 0.0f, nullptr, 0, 0, nullptr, 0);
    k_prop<<<782, 256, 0, stream>>>(cnt, slots, uv, 32, 16, Hc2, 48, 0, 2, 2.0f,
                                    P, 48, 0, 1.0f, uv, 32, 0, b1, 1);
    k_bnstats<<<256, 256, 0, stream>>>(Hc2, 48, 4, stats1);
    k_bnapply<<<3125, 256, 0, stream>>>(Hc2, 48, 4, stats1, g1, be1);

    // ---- Layer 2 (16->32)
    k_prop<<<782, 256, 0, stream>>>(cnt, slots, Hc2, 48, 0, Hc2, 48, 16, 2, 1.0f,
                                    nullptr, 0, 0, 0.0f, nullptr, 0, 0, nullptr, 0);
    k_prop<<<782, 256, 0, stream>>>(cnt, slots, Hc2, 48, 16, Hc2, 48, 32, 2, 2.0f,
                                    Hc2, 48, 0, -1.0f, nullptr, 0, 0, nullptr, 0);
    k_gemm<<<dim3(1, 391), 256, 0, stream>>>(Hc2, 48, W2, 32, Hc3, 96, NN, 48, 32, b2, 1);
    k_bnstats<<<256, 256, 0, stream>>>(Hc3, 96, 5, stats2);
    k_bnapply<<<6250, 256, 0, stream>>>(Hc3, 96, 5, stats2, g2, be2);

    // ---- Layer 3 (32->64)
    k_prop<<<1563, 256, 0, stream>>>(cnt, slots, Hc3, 96, 0, Hc3, 96, 32, 3, 1.0f,
                                     nullptr, 0, 0, 0.0f, nullptr, 0, 0, nullptr, 0);
    k_prop<<<1563, 256, 0, stream>>>(cnt, slots, Hc3, 96, 32, Hc3, 96, 64, 3, 2.0f,
                                     Hc3, 96, 0, -1.0f, nullptr, 0, 0, nullptr, 0);
    k_gemm_mfma_bf<<<dim3(1, 391), 256, 0, stream>>>(Hc3, 96, bt3h, bt3l, Hc4, 192, NN, 96, 64, b3, 1, 0);
    k_bnstats<<<256, 256, 0, stream>>>(Hc4, 192, 6, stats3);
    k_bnapply<<<12500, 256, 0, stream>>>(Hc4, 192, 6, stats3, g3, be3);

    // ---- Layer 4 (64->128)
    k_prop<<<3125, 256, 0, stream>>>(cnt, slots, Hc4, 192, 0, Hc4, 192, 64, 4, 1.0f,
                                     nullptr, 0, 0, 0.0f, nullptr, 0, 0, nullptr, 0);
    k_prop<<<3125, 256, 0, stream>>>(cnt, slots, Hc4, 192, 64, Hc4, 192, 128, 4, 2.0f,
                                     Hc4, 192, 0, -1.0f, nullptr, 0, 0, nullptr, 0);
    k_gemm_mfma_bf<<<dim3(1, 391), 256, 0, stream>>>(Hc4, 192, bt4h, bt4l, Hc5, 384, NN, 192, 128, b4, 1, 0);
    k_bnstats<<<256, 256, 0, stream>>>(Hc5, 384, 7, stats4);
    k_bnapply<<<25000, 256, 0, stream>>>(Hc5, 384, 7, stats4, g4, be4);

    // ---- Layer 5 (128->256), no BN/act, fp32 output
    k_prop<<<6250, 256, 0, stream>>>(cnt, slots, Hc5, 384, 0, Hc5, 384, 128, 5, 1.0f,
                                     nullptr, 0, 0, 0.0f, nullptr, 0, 0, nullptr, 0);
    k_prop<<<6250, 256, 0, stream>>>(cnt, slots, Hc5, 384, 128, Hc5, 384, 256, 5, 2.0f,
                                     Hc5, 384, 0, -1.0f, nullptr, 0, 0, nullptr, 0);
    k_gemm_mfma_bf<<<dim3(2, 391), 256, 0, stream>>>(Hc5, 384, bt5h, bt5l, h5, 256, NN, 384, 256, b5, 0, 1);

    // ---- Pool + dense + log_softmax
    k_pool1<<<dim3(16, 64), 256, 0, stream>>>(h5, gb, partial);
    k_pool2d<<<64, 256, 0, stream>>>(partial, gb, Wd, bd, outp);
}